// Round 1
// baseline (581.943 us; speedup 1.0000x reference)
//
#include <hip/hip_runtime.h>
#include <hip/hip_bf16.h>
#include <cstdint>
#include <cstddef>

// Shapes (fixed): B=8, LB=512, LC=128, H=256, H2=512, MIN_WS=5, N_WIN=4
// Windows: ws=5,10,15,20 ; n_seg=102,101,100,99 ; total 402
// d_out: out[8*256] | s_score[8*402] | b_score[8*512]  (floats)

#define BM 64
#define BN 64
#define BK 16

__device__ __forceinline__ float fsigmoid(float x) { return 1.0f / (1.0f + __expf(-x)); }
__device__ __forceinline__ float ftanh(float x) {
  float e = __expf(2.0f * x);
  return 1.0f - 2.0f / (e + 1.0f);
}

// ---------------- concat: [enc | broadcast c_state] -> X0 (M x 512) -------------
__global__ __launch_bounds__(256) void concat_k(const float* __restrict__ enc,
                                                const float* __restrict__ cs,
                                                float* __restrict__ out, int Lshift) {
  int idx = blockIdx.x * 256 + threadIdx.x;   // over M*512
  int row = idx >> 9, col = idx & 511;
  float v;
  if (col < 256) v = enc[((size_t)row << 8) + col];
  else           v = cs[((size_t)(row >> Lshift) << 8) + (col - 256)];
  out[idx] = v;
}

// ---------------- GEMM: Y = act(X @ W{0..NB-1} + b) ----------------------------
// NB=3 + HWY: highway epilogue  y = g*relu(n) + (1-g)*l
// NB=1: linear (+optional bias)
template <int NB, bool HWY>
__global__ __launch_bounds__(256) void gemm_k(
    const float* __restrict__ X,
    const float* __restrict__ W0, const float* __restrict__ W1, const float* __restrict__ W2,
    const float* __restrict__ B0, const float* __restrict__ B1, const float* __restrict__ B2,
    float* __restrict__ Y, int M, int N, int K) {
  __shared__ float As[BK][BM];         // transposed: As[k][m]
  __shared__ float Bs[NB][BK][BN];
  const int tid = threadIdx.x;
  const int m0 = blockIdx.y * BM, n0 = blockIdx.x * BN;
  const int tx = tid & 15, ty = tid >> 4;

  float acc[NB][4][4];
#pragma unroll
  for (int p = 0; p < NB; ++p)
#pragma unroll
    for (int i = 0; i < 4; ++i)
#pragma unroll
      for (int j = 0; j < 4; ++j) acc[p][i][j] = 0.f;

  const int arow = tid >> 2, ak = (tid & 3) << 2;
  const int brow = tid >> 4, bc = (tid & 15) << 2;

  for (int k0 = 0; k0 < K; k0 += BK) {
    float4 av = *(const float4*)(X + (size_t)(m0 + arow) * K + (k0 + ak));
    float4 bv0 = *(const float4*)(W0 + (size_t)(k0 + brow) * N + (n0 + bc));
    float4 bv1, bv2;
    if constexpr (NB == 3) {
      bv1 = *(const float4*)(W1 + (size_t)(k0 + brow) * N + (n0 + bc));
      bv2 = *(const float4*)(W2 + (size_t)(k0 + brow) * N + (n0 + bc));
    }
    __syncthreads();
    As[ak + 0][arow] = av.x; As[ak + 1][arow] = av.y;
    As[ak + 2][arow] = av.z; As[ak + 3][arow] = av.w;
    *(float4*)&Bs[0][brow][bc] = bv0;
    if constexpr (NB == 3) {
      *(float4*)&Bs[1][brow][bc] = bv1;
      *(float4*)&Bs[2][brow][bc] = bv2;
    }
    __syncthreads();
#pragma unroll
    for (int k = 0; k < BK; ++k) {
      float4 a = *(const float4*)&As[k][ty << 2];
      float ar[4] = {a.x, a.y, a.z, a.w};
#pragma unroll
      for (int p = 0; p < NB; ++p) {
        float4 bb = *(const float4*)&Bs[p][k][tx << 2];
#pragma unroll
        for (int i = 0; i < 4; ++i) {
          acc[p][i][0] += ar[i] * bb.x;
          acc[p][i][1] += ar[i] * bb.y;
          acc[p][i][2] += ar[i] * bb.z;
          acc[p][i][3] += ar[i] * bb.w;
        }
      }
    }
  }

#pragma unroll
  for (int i = 0; i < 4; ++i) {
    int row = m0 + (ty << 2) + i;
#pragma unroll
    for (int j = 0; j < 4; ++j) {
      int col = n0 + (tx << 2) + j;
      float y;
      if constexpr (HWY) {
        float nv = acc[0][i][j] + B0[col];
        float lv = acc[1][i][j] + B1[col];
        float gv = fsigmoid(acc[2][i][j] + B2[col]);
        y = gv * fmaxf(nv, 0.f) + (1.f - gv) * lv;
      } else {
        y = acc[0][i][j] + (B0 ? B0[col] : 0.f);
      }
      Y[(size_t)row * N + col] = y;
    }
  }
}

// -------- m-score: b_score[row] = max_j sum_h tanh(wq[row,h]+uh[b,j,h])*v[h] ----
__global__ __launch_bounds__(256) void mscore_k(const float* __restrict__ wq,  // 4096x512
                                                const float* __restrict__ uh,  // 8x128x512
                                                const float* __restrict__ mv,  // 512
                                                float* __restrict__ bscore) {  // 4096
  __shared__ float uhs[16][512];   // 32 KB tile of uh[b]
  const int tid = threadIdx.x, lane = tid & 63, wid = tid >> 6;
  const int row = blockIdx.x * 4 + wid;   // 0..4095 (b = row>>9, all 4 waves same b)
  const int b = row >> 9;
  const int h0 = lane << 3;               // 8 contiguous h per lane
  const float* wrow = wq + (size_t)row * 512 + h0;
  float4 w0 = *(const float4*)(wrow);
  float4 w1 = *(const float4*)(wrow + 4);
  float4 v0 = *(const float4*)(mv + h0);
  float4 v1 = *(const float4*)(mv + h0 + 4);

  float mmax = -3.0e38f;
  for (int jt = 0; jt < 8; ++jt) {        // 128 j in tiles of 16
    __syncthreads();
#pragma unroll
    for (int t = 0; t < 8; ++t) {         // 256 thr * 8 float4 = 16x512
      int f4 = tid + (t << 8);
      int r = f4 >> 7, c4 = (f4 & 127) << 2;
      *(float4*)&uhs[r][c4] =
          *(const float4*)(uh + ((size_t)(b * 128 + (jt << 4) + r)) * 512 + c4);
    }
    __syncthreads();
    for (int jj = 0; jj < 16; ++jj) {
      float4 u0 = *(const float4*)&uhs[jj][h0];
      float4 u1 = *(const float4*)&uhs[jj][h0 + 4];
      float s = ftanh(w0.x + u0.x) * v0.x + ftanh(w0.y + u0.y) * v0.y +
                ftanh(w0.z + u0.z) * v0.z + ftanh(w0.w + u0.w) * v0.w +
                ftanh(w1.x + u1.x) * v1.x + ftanh(w1.y + u1.y) * v1.y +
                ftanh(w1.z + u1.z) * v1.z + ftanh(w1.w + u1.w) * v1.w;
#pragma unroll
      for (int off = 32; off; off >>= 1) s += __shfl_xor(s, off);
      mmax = fmaxf(mmax, s);
    }
  }
  if (lane == 0) bscore[row] = mmax;
}

// -------- wq_a[b,h] = sum_k c_state[b,k]*a_Wq[k,h] + a_bq[h] -------------------
__global__ __launch_bounds__(256) void wqa_k(const float* __restrict__ cs,
                                             const float* __restrict__ Wq,
                                             const float* __restrict__ bq,
                                             float* __restrict__ wqa) {
  int b = blockIdx.x, h = threadIdx.x;
  float acc = bq[h];
  for (int k = 0; k < 256; ++k) acc += cs[b * 256 + k] * Wq[k * 256 + h];
  wqa[b * 256 + h] = acc;
}

// -------- t[pos] = sum_h tanh(wqa[b,h]+uha[pos,h])*a_v[h] ----------------------
__global__ __launch_bounds__(256) void tscore_k(const float* __restrict__ uha,  // 4096x256
                                                const float* __restrict__ wqa,  // 8x256
                                                const float* __restrict__ av,   // 256
                                                float* __restrict__ t) {        // 4096
  const int tid = threadIdx.x, lane = tid & 63, wid = tid >> 6;
  const int pos = blockIdx.x * 4 + wid;
  const int b = pos >> 9;
  const int h0 = lane << 2;
  float4 u = *(const float4*)(uha + (size_t)pos * 256 + h0);
  float4 w = *(const float4*)(wqa + b * 256 + h0);
  float4 v = *(const float4*)(av + h0);
  float s = ftanh(w.x + u.x) * v.x + ftanh(w.y + u.y) * v.y +
            ftanh(w.z + u.z) * v.z + ftanh(w.w + u.w) * v.w;
#pragma unroll
  for (int off = 32; off; off >>= 1) s += __shfl_xor(s, off);
  if (lane == 0) t[pos] = s;
}

// -------- per-segment: softmax over window of t, weighted sum of b_enc rows ----
__global__ __launch_bounds__(256) void seg_k(const float* __restrict__ t,       // 4096
                                             const float* __restrict__ bscore,  // 4096
                                             const float* __restrict__ benc,    // 8x512x256
                                             float* __restrict__ seg,           // 8x402x256
                                             float* __restrict__ sco) {         // 8x402
  const int s = blockIdx.x, b = blockIdx.y, h = threadIdx.x;
  int i, n;
  if (s < 102)      { i = 0; n = s; }
  else if (s < 203) { i = 1; n = s - 102; }
  else if (s < 303) { i = 2; n = s - 203; }
  else              { i = 3; n = s - 303; }
  const int ws = 5 * (i + 1), start = n * 5;
  const float* tb = t + b * 512 + start;
  float mx = -3.0e38f;
  for (int w = 0; w < ws; ++w) mx = fmaxf(mx, tb[w]);
  float sum = 0.f;
  for (int w = 0; w < ws; ++w) sum += __expf(tb[w] - mx);
  float inv = 1.f / sum;
  float acc = 0.f;
  for (int w = 0; w < ws; ++w)
    acc += __expf(tb[w] - mx) * benc[((size_t)(b * 512 + start + w)) * 256 + h];
  seg[((size_t)(b * 402 + s)) * 256 + h] = acc * inv;
  if (h == 0) {
    float ss = 0.f;
    const float* bs = bscore + b * 512 + start;
    for (int w = 0; w < ws; ++w) ss += bs[w];
    sco[b * 402 + s] = ss;
  }
}

// -------- final: s_score = softmax(scores); out = s_score @ segments -----------
__global__ __launch_bounds__(256) void final_k(const float* __restrict__ sco,  // 8x402
                                               const float* __restrict__ seg,  // 8x402x256
                                               float* __restrict__ dout) {
  const int b = blockIdx.x, tid = threadIdx.x, lane = tid & 63, wid = tid >> 6;
  __shared__ float sc[402];
  __shared__ float redm[4], reds[4];
  for (int s = tid; s < 402; s += 256) sc[s] = sco[b * 402 + s];
  __syncthreads();
  float m = -3.0e38f;
  for (int s = tid; s < 402; s += 256) m = fmaxf(m, sc[s]);
#pragma unroll
  for (int off = 32; off; off >>= 1) m = fmaxf(m, __shfl_xor(m, off));
  if (lane == 0) redm[wid] = m;
  __syncthreads();
  m = fmaxf(fmaxf(redm[0], redm[1]), fmaxf(redm[2], redm[3]));
  float p = 0.f;
  for (int s = tid; s < 402; s += 256) p += __expf(sc[s] - m);
#pragma unroll
  for (int off = 32; off; off >>= 1) p += __shfl_xor(p, off);
  if (lane == 0) reds[wid] = p;
  __syncthreads();
  float invS = 1.f / (reds[0] + reds[1] + reds[2] + reds[3]);
  for (int s = tid; s < 402; s += 256) {
    float pv = __expf(sc[s] - m) * invS;
    dout[2048 + b * 402 + s] = pv;   // s_score
    sc[s] = pv;
  }
  __syncthreads();
  float acc = 0.f;
  for (int s = 0; s < 402; ++s)
    acc += sc[s] * seg[((size_t)(b * 402 + s)) * 256 + tid];
  dout[b * 256 + tid] = acc;         // out
}

extern "C" void kernel_launch(void* const* d_in, const int* in_sizes, int n_in,
                              void* d_out, int out_size, void* d_ws, size_t ws_size,
                              hipStream_t stream) {
  const float* b_enc   = (const float*)d_in[0];   // 8x512x256
  const float* c_enc   = (const float*)d_in[1];   // 8x128x256
  const float* c_state = (const float*)d_in[2];   // 8x1x256
  // d_in[3], d_in[4]: b_mask/c_mask — all-true in this problem, ignored.
  const float* bh_Wn = (const float*)d_in[5];
  const float* bh_bn = (const float*)d_in[6];
  const float* bh_Wl = (const float*)d_in[7];
  const float* bh_bl = (const float*)d_in[8];
  const float* bh_Wg = (const float*)d_in[9];
  const float* bh_bg = (const float*)d_in[10];
  const float* ch_Wn = (const float*)d_in[11];
  const float* ch_bn = (const float*)d_in[12];
  const float* ch_Wl = (const float*)d_in[13];
  const float* ch_bl = (const float*)d_in[14];
  const float* ch_Wg = (const float*)d_in[15];
  const float* ch_bg = (const float*)d_in[16];
  const float* m_Wq  = (const float*)d_in[17];
  const float* m_bq  = (const float*)d_in[18];
  const float* m_Wk  = (const float*)d_in[19];
  const float* m_v   = (const float*)d_in[20];
  const float* a_Wq  = (const float*)d_in[21];
  const float* a_bq  = (const float*)d_in[22];
  const float* a_Wk  = (const float*)d_in[23];
  const float* a_v   = (const float*)d_in[24];

  float* ws  = (float*)d_ws;
  float* XB0 = ws;                  // 4096*512
  float* XB1 = XB0 + 2097152;       // 4096*512
  float* XC0 = XB1 + 2097152;       // 1024*512
  float* XC1 = XC0 + 524288;        // 1024*512
  float* UHA = XC1 + 524288;        // 4096*256
  float* WQA = UHA + 1048576;       // 8*256
  float* T   = WQA + 2048;          // 4096
  float* SEG = T + 4096;            // 8*402*256
  float* SCO = SEG + 823296;        // 8*402

  float* out = (float*)d_out;
  float* BSC = out + 5264;          // b_score region of d_out

  const int LW = 262144;            // 512*512 per-layer weight stride

  concat_k<<<8192, 256, 0, stream>>>(b_enc, c_state, XB0, 9);
  concat_k<<<2048, 256, 0, stream>>>(c_enc, c_state, XC0, 7);

  // highway b (2 layers), highway c (2 layers) — fused 3-matmul + gate epilogue
  gemm_k<3, true><<<dim3(8, 64), 256, 0, stream>>>(XB0, bh_Wn, bh_Wl, bh_Wg,
      bh_bn, bh_bl, bh_bg, XB1, 4096, 512, 512);
  gemm_k<3, true><<<dim3(8, 64), 256, 0, stream>>>(XB1, bh_Wn + LW, bh_Wl + LW, bh_Wg + LW,
      bh_bn + 512, bh_bl + 512, bh_bg + 512, XB0, 4096, 512, 512);
  gemm_k<3, true><<<dim3(8, 16), 256, 0, stream>>>(XC0, ch_Wn, ch_Wl, ch_Wg,
      ch_bn, ch_bl, ch_bg, XC1, 1024, 512, 512);
  gemm_k<3, true><<<dim3(8, 16), 256, 0, stream>>>(XC1, ch_Wn + LW, ch_Wl + LW, ch_Wg + LW,
      ch_bn + 512, ch_bl + 512, ch_bg + 512, XC0, 1024, 512, 512);

  // m path: wq_m = b@m_Wq + m_bq ; uh_m = c@m_Wk ; then tanh-reduce-max
  gemm_k<1, false><<<dim3(8, 64), 256, 0, stream>>>(XB0, m_Wq, nullptr, nullptr,
      m_bq, nullptr, nullptr, XB1, 4096, 512, 512);
  gemm_k<1, false><<<dim3(8, 16), 256, 0, stream>>>(XC0, m_Wk, nullptr, nullptr,
      nullptr, nullptr, nullptr, XC1, 1024, 512, 512);
  mscore_k<<<1024, 256, 0, stream>>>(XB1, XC1, m_v, BSC);

  // window path: uh_a over full b_enc once (windows are gathers of positions)
  gemm_k<1, false><<<dim3(4, 64), 256, 0, stream>>>(b_enc, a_Wk, nullptr, nullptr,
      nullptr, nullptr, nullptr, UHA, 4096, 256, 256);
  wqa_k<<<8, 256, 0, stream>>>(c_state, a_Wq, a_bq, WQA);
  tscore_k<<<1024, 256, 0, stream>>>(UHA, WQA, a_v, T);
  seg_k<<<dim3(402, 8), 256, 0, stream>>>(T, BSC, b_enc, SEG, SCO);
  final_k<<<8, 256, 0, stream>>>(SCO, SEG, out);
}

// Round 2
// 471.511 us; speedup vs baseline: 1.2342x; 1.2342x over previous
//
#include <hip/hip_runtime.h>
#include <hip/hip_bf16.h>
#include <cstdint>
#include <cstddef>

// Shapes (fixed): B=8, LB=512, LC=128, H=256, H2=512, MIN_WS=5, N_WIN=4
// Windows: ws=5,10,15,20 ; n_seg=102,101,100,99 ; total 402
// d_out: out[8*256] | s_score[8*402] | b_score[8*512]  (floats)

#define BM 64
#define BN 64
#define BK 16

__device__ __forceinline__ float fsigmoid(float x) { return 1.0f / (1.0f + __expf(-x)); }
__device__ __forceinline__ float ftanh(float x) {
  float e = __expf(2.0f * x);
  return 1.0f - 2.0f / (e + 1.0f);
}

// ---------------- concat: [enc | broadcast c_state] -> X0 (M x 512) -------------
__global__ __launch_bounds__(256) void concat_k(const float* __restrict__ enc,
                                                const float* __restrict__ cs,
                                                float* __restrict__ out, int Lshift) {
  int idx = blockIdx.x * 256 + threadIdx.x;   // over M*512
  int row = idx >> 9, col = idx & 511;
  float v;
  if (col < 256) v = enc[((size_t)row << 8) + col];
  else           v = cs[((size_t)(row >> Lshift) << 8) + (col - 256)];
  out[idx] = v;
}

// ---------------- GEMM: Y = epi(X @ W{0..NB-1} + b) ----------------------------
// EPI=0: plain (+optional bias)     EPI=1: highway  y = g*relu(n)+(1-g)*l
// EPI=2: exp(2*(acc+bias)), row-major
// EPI=3: exp(2*acc), transposed write Y[b][col][row&127]  (for UHT, M=1024,N=512)
template <int NB, int EPI>
__global__ __launch_bounds__(256) void gemm_k(
    const float* __restrict__ X,
    const float* __restrict__ W0, const float* __restrict__ W1, const float* __restrict__ W2,
    const float* __restrict__ B0, const float* __restrict__ B1, const float* __restrict__ B2,
    float* __restrict__ Y, int M, int N, int K) {
  __shared__ float As[BK][BM];         // transposed: As[k][m]
  __shared__ float Bs[NB][BK][BN];
  const int tid = threadIdx.x;
  const int m0 = blockIdx.y * BM, n0 = blockIdx.x * BN;
  const int tx = tid & 15, ty = tid >> 4;

  float acc[NB][4][4];
#pragma unroll
  for (int p = 0; p < NB; ++p)
#pragma unroll
    for (int i = 0; i < 4; ++i)
#pragma unroll
      for (int j = 0; j < 4; ++j) acc[p][i][j] = 0.f;

  const int arow = tid >> 2, ak = (tid & 3) << 2;
  const int brow = tid >> 4, bc = (tid & 15) << 2;

  for (int k0 = 0; k0 < K; k0 += BK) {
    float4 av = *(const float4*)(X + (size_t)(m0 + arow) * K + (k0 + ak));
    float4 bv0 = *(const float4*)(W0 + (size_t)(k0 + brow) * N + (n0 + bc));
    float4 bv1, bv2;
    if constexpr (NB == 3) {
      bv1 = *(const float4*)(W1 + (size_t)(k0 + brow) * N + (n0 + bc));
      bv2 = *(const float4*)(W2 + (size_t)(k0 + brow) * N + (n0 + bc));
    }
    __syncthreads();
    As[ak + 0][arow] = av.x; As[ak + 1][arow] = av.y;
    As[ak + 2][arow] = av.z; As[ak + 3][arow] = av.w;
    *(float4*)&Bs[0][brow][bc] = bv0;
    if constexpr (NB == 3) {
      *(float4*)&Bs[1][brow][bc] = bv1;
      *(float4*)&Bs[2][brow][bc] = bv2;
    }
    __syncthreads();
#pragma unroll
    for (int k = 0; k < BK; ++k) {
      float4 a = *(const float4*)&As[k][ty << 2];
      float ar[4] = {a.x, a.y, a.z, a.w};
#pragma unroll
      for (int p = 0; p < NB; ++p) {
        float4 bb = *(const float4*)&Bs[p][k][tx << 2];
#pragma unroll
        for (int i = 0; i < 4; ++i) {
          acc[p][i][0] += ar[i] * bb.x;
          acc[p][i][1] += ar[i] * bb.y;
          acc[p][i][2] += ar[i] * bb.z;
          acc[p][i][3] += ar[i] * bb.w;
        }
      }
    }
  }

  if constexpr (EPI == 3) {
    // transposed write: Y[(row>>7)*65536 + col*128 + (row&127)], exp(2x)
    const int row0 = m0 + (ty << 2);
    float* base = Y + (((size_t)(row0 >> 7)) << 16) + (row0 & 127);
#pragma unroll
    for (int j = 0; j < 4; ++j) {
      int col = n0 + (tx << 2) + j;
      float4 w;
      w.x = __expf(2.0f * acc[0][0][j]);
      w.y = __expf(2.0f * acc[0][1][j]);
      w.z = __expf(2.0f * acc[0][2][j]);
      w.w = __expf(2.0f * acc[0][3][j]);
      *(float4*)(base + ((size_t)col << 7)) = w;
    }
  } else {
#pragma unroll
    for (int i = 0; i < 4; ++i) {
      int row = m0 + (ty << 2) + i;
#pragma unroll
      for (int j = 0; j < 4; ++j) {
        int col = n0 + (tx << 2) + j;
        float y;
        if constexpr (EPI == 1) {
          float nv = acc[0][i][j] + B0[col];
          float lv = acc[1][i][j] + B1[col];
          float gv = fsigmoid(acc[2][i][j] + B2[col]);
          y = gv * fmaxf(nv, 0.f) + (1.f - gv) * lv;
        } else if constexpr (EPI == 2) {
          y = __expf(2.0f * (acc[0][i][j] + B0[col]));
        } else {
          y = acc[0][i][j] + (B0 ? B0[col] : 0.f);
        }
        Y[(size_t)row * N + col] = y;
      }
    }
  }
}

// -------- m-score via tanh factorization ---------------------------------------
// tanh(a+b) = 1 - 2/(1 + e^{2a} e^{2b});  m[row,j] = V - 2 * sum_h v[h]/(1+Ew*Eu)
// b_score[row] = max_j m = V - 2 * min_j t_j
// EW:  [4096][512]  = exp(2*(b@m_Wq+bq))      (row-major)
// UHT: [8][512][128] = exp(2*(c@m_Wk)) transposed (h-major)
__global__ __launch_bounds__(256) void mscore_k(const float* __restrict__ EW,
                                                const float* __restrict__ UHT,
                                                const float* __restrict__ mv,   // 512
                                                float* __restrict__ bscore) {   // 4096
  __shared__ float eus[64 * 128];   // 32 KB chunk: Eu[h0..h0+63][j=0..127]
  const int tid = threadIdx.x, lane = tid & 63, wid = tid >> 6;
  const int row = __builtin_amdgcn_readfirstlane(blockIdx.x * 4 + wid);
  const int b = row >> 9;
  const float* ew = EW + ((size_t)row << 9);
  const float* eub = UHT + ((size_t)b << 16);

  // V = sum_h v[h]
  float V = 0.f;
#pragma unroll
  for (int k = 0; k < 8; ++k) V += mv[lane + (k << 6)];
#pragma unroll
  for (int off = 32; off; off >>= 1) V += __shfl_xor(V, off);

  float t0 = 0.f, t1 = 0.f;
  for (int c = 0; c < 8; ++c) {
    __syncthreads();
#pragma unroll
    for (int it = 0; it < 8; ++it) {      // 2048 float4 = 64*128 floats
      int f4 = it * 256 + tid;
      *(float4*)&eus[f4 << 2] = *(const float4*)(eub + ((size_t)c << 13) + (f4 << 2));
    }
    __syncthreads();
#pragma unroll 8
    for (int h = 0; h < 64; ++h) {
      float e = ew[(c << 6) + h];         // s_load (wave-uniform)
      float vv = mv[(c << 6) + h];        // s_load
      float u0 = eus[(h << 7) + lane];
      float u1 = eus[(h << 7) + lane + 64];
      t0 += vv * __builtin_amdgcn_rcpf(__builtin_fmaf(e, u0, 1.f));
      t1 += vv * __builtin_amdgcn_rcpf(__builtin_fmaf(e, u1, 1.f));
    }
  }
  float t = fminf(t0, t1);
#pragma unroll
  for (int off = 32; off; off >>= 1) t = fminf(t, __shfl_xor(t, off));
  if (lane == 0) bscore[row] = V - 2.f * t;
}

// -------- wq_a[b,h] = sum_k c_state[b,k]*a_Wq[k,h] + a_bq[h] -------------------
__global__ __launch_bounds__(256) void wqa_k(const float* __restrict__ cs,
                                             const float* __restrict__ Wq,
                                             const float* __restrict__ bq,
                                             float* __restrict__ wqa) {
  int b = blockIdx.x, h = threadIdx.x;
  float acc = bq[h];
  for (int k = 0; k < 256; ++k) acc += cs[b * 256 + k] * Wq[k * 256 + h];
  wqa[b * 256 + h] = acc;
}

// -------- t[pos] = sum_h tanh(wqa[b,h]+uha[pos,h])*a_v[h] ----------------------
__global__ __launch_bounds__(256) void tscore_k(const float* __restrict__ uha,  // 4096x256
                                                const float* __restrict__ wqa,  // 8x256
                                                const float* __restrict__ av,   // 256
                                                float* __restrict__ t) {        // 4096
  const int tid = threadIdx.x, lane = tid & 63, wid = tid >> 6;
  const int pos = blockIdx.x * 4 + wid;
  const int b = pos >> 9;
  const int h0 = lane << 2;
  float4 u = *(const float4*)(uha + (size_t)pos * 256 + h0);
  float4 w = *(const float4*)(wqa + b * 256 + h0);
  float4 v = *(const float4*)(av + h0);
  float s = ftanh(w.x + u.x) * v.x + ftanh(w.y + u.y) * v.y +
            ftanh(w.z + u.z) * v.z + ftanh(w.w + u.w) * v.w;
#pragma unroll
  for (int off = 32; off; off >>= 1) s += __shfl_xor(s, off);
  if (lane == 0) t[pos] = s;
}

// -------- per-segment: softmax over window of t, weighted sum of b_enc rows ----
__global__ __launch_bounds__(256) void seg_k(const float* __restrict__ t,       // 4096
                                             const float* __restrict__ bscore,  // 4096
                                             const float* __restrict__ benc,    // 8x512x256
                                             float* __restrict__ seg,           // 8x402x256
                                             float* __restrict__ sco) {         // 8x402
  const int s = blockIdx.x, b = blockIdx.y, h = threadIdx.x;
  int i, n;
  if (s < 102)      { i = 0; n = s; }
  else if (s < 203) { i = 1; n = s - 102; }
  else if (s < 303) { i = 2; n = s - 203; }
  else              { i = 3; n = s - 303; }
  const int ws = 5 * (i + 1), start = n * 5;
  const float* tb = t + b * 512 + start;
  float mx = -3.0e38f;
  for (int w = 0; w < ws; ++w) mx = fmaxf(mx, tb[w]);
  float sum = 0.f;
  for (int w = 0; w < ws; ++w) sum += __expf(tb[w] - mx);
  float inv = 1.f / sum;
  float acc = 0.f;
  for (int w = 0; w < ws; ++w)
    acc += __expf(tb[w] - mx) * benc[((size_t)(b * 512 + start + w)) * 256 + h];
  seg[((size_t)(b * 402 + s)) * 256 + h] = acc * inv;
  if (h == 0) {
    float ss = 0.f;
    const float* bs = bscore + b * 512 + start;
    for (int w = 0; w < ws; ++w) ss += bs[w];
    sco[b * 402 + s] = ss;
  }
}

// -------- final: s_score = softmax(scores); out = s_score @ segments -----------
__global__ __launch_bounds__(256) void final_k(const float* __restrict__ sco,  // 8x402
                                               const float* __restrict__ seg,  // 8x402x256
                                               float* __restrict__ dout) {
  const int b = blockIdx.x, tid = threadIdx.x, lane = tid & 63, wid = tid >> 6;
  __shared__ float sc[402];
  __shared__ float redm[4], reds[4];
  for (int s = tid; s < 402; s += 256) sc[s] = sco[b * 402 + s];
  __syncthreads();
  float m = -3.0e38f;
  for (int s = tid; s < 402; s += 256) m = fmaxf(m, sc[s]);
#pragma unroll
  for (int off = 32; off; off >>= 1) m = fmaxf(m, __shfl_xor(m, off));
  if (lane == 0) redm[wid] = m;
  __syncthreads();
  m = fmaxf(fmaxf(redm[0], redm[1]), fmaxf(redm[2], redm[3]));
  float p = 0.f;
  for (int s = tid; s < 402; s += 256) p += __expf(sc[s] - m);
#pragma unroll
  for (int off = 32; off; off >>= 1) p += __shfl_xor(p, off);
  if (lane == 0) reds[wid] = p;
  __syncthreads();
  float invS = 1.f / (reds[0] + reds[1] + reds[2] + reds[3]);
  for (int s = tid; s < 402; s += 256) {
    float pv = __expf(sc[s] - m) * invS;
    dout[2048 + b * 402 + s] = pv;   // s_score
    sc[s] = pv;
  }
  __syncthreads();
  float acc = 0.f;
  for (int s = 0; s < 402; ++s)
    acc += sc[s] * seg[((size_t)(b * 402 + s)) * 256 + tid];
  dout[b * 256 + tid] = acc;         // out
}

extern "C" void kernel_launch(void* const* d_in, const int* in_sizes, int n_in,
                              void* d_out, int out_size, void* d_ws, size_t ws_size,
                              hipStream_t stream) {
  const float* b_enc   = (const float*)d_in[0];   // 8x512x256
  const float* c_enc   = (const float*)d_in[1];   // 8x128x256
  const float* c_state = (const float*)d_in[2];   // 8x1x256
  // d_in[3], d_in[4]: b_mask/c_mask — all-true in this problem, ignored.
  const float* bh_Wn = (const float*)d_in[5];
  const float* bh_bn = (const float*)d_in[6];
  const float* bh_Wl = (const float*)d_in[7];
  const float* bh_bl = (const float*)d_in[8];
  const float* bh_Wg = (const float*)d_in[9];
  const float* bh_bg = (const float*)d_in[10];
  const float* ch_Wn = (const float*)d_in[11];
  const float* ch_bn = (const float*)d_in[12];
  const float* ch_Wl = (const float*)d_in[13];
  const float* ch_bl = (const float*)d_in[14];
  const float* ch_Wg = (const float*)d_in[15];
  const float* ch_bg = (const float*)d_in[16];
  const float* m_Wq  = (const float*)d_in[17];
  const float* m_bq  = (const float*)d_in[18];
  const float* m_Wk  = (const float*)d_in[19];
  const float* m_v   = (const float*)d_in[20];
  const float* a_Wq  = (const float*)d_in[21];
  const float* a_bq  = (const float*)d_in[22];
  const float* a_Wk  = (const float*)d_in[23];
  const float* a_v   = (const float*)d_in[24];

  float* ws  = (float*)d_ws;
  float* XB0 = ws;                  // 4096*512
  float* XB1 = XB0 + 2097152;       // 4096*512  (also EW)
  float* XC0 = XB1 + 2097152;       // 1024*512
  float* XC1 = XC0 + 524288;        // 1024*512  (also UHT: 8x512x128)
  float* UHA = XC1 + 524288;        // 4096*256
  float* WQA = UHA + 1048576;       // 8*256
  float* T   = WQA + 2048;          // 4096
  float* SEG = T + 4096;            // 8*402*256
  float* SCO = SEG + 823296;        // 8*402

  float* out = (float*)d_out;
  float* BSC = out + 5264;          // b_score region of d_out

  const int LW = 262144;            // 512*512 per-layer weight stride

  concat_k<<<8192, 256, 0, stream>>>(b_enc, c_state, XB0, 9);
  concat_k<<<2048, 256, 0, stream>>>(c_enc, c_state, XC0, 7);

  // highway b (2 layers), highway c (2 layers) — fused 3-matmul + gate epilogue
  gemm_k<3, 1><<<dim3(8, 64), 256, 0, stream>>>(XB0, bh_Wn, bh_Wl, bh_Wg,
      bh_bn, bh_bl, bh_bg, XB1, 4096, 512, 512);
  gemm_k<3, 1><<<dim3(8, 64), 256, 0, stream>>>(XB1, bh_Wn + LW, bh_Wl + LW, bh_Wg + LW,
      bh_bn + 512, bh_bl + 512, bh_bg + 512, XB0, 4096, 512, 512);
  gemm_k<3, 1><<<dim3(8, 16), 256, 0, stream>>>(XC0, ch_Wn, ch_Wl, ch_Wg,
      ch_bn, ch_bl, ch_bg, XC1, 1024, 512, 512);
  gemm_k<3, 1><<<dim3(8, 16), 256, 0, stream>>>(XC1, ch_Wn + LW, ch_Wl + LW, ch_Wg + LW,
      ch_bn + 512, ch_bl + 512, ch_bg + 512, XC0, 1024, 512, 512);

  // m path: EW = exp(2*(b@m_Wq+bq)) ; UHT = exp(2*(c@m_Wk))^T ; then rcp-reduce
  gemm_k<1, 2><<<dim3(8, 64), 256, 0, stream>>>(XB0, m_Wq, nullptr, nullptr,
      m_bq, nullptr, nullptr, XB1, 4096, 512, 512);
  gemm_k<1, 3><<<dim3(8, 16), 256, 0, stream>>>(XC0, m_Wk, nullptr, nullptr,
      nullptr, nullptr, nullptr, XC1, 1024, 512, 512);
  mscore_k<<<1024, 256, 0, stream>>>(XB1, XC1, m_v, BSC);

  // window path: uh_a over full b_enc once (windows are gathers of positions)
  gemm_k<1, 0><<<dim3(4, 64), 256, 0, stream>>>(b_enc, a_Wk, nullptr, nullptr,
      nullptr, nullptr, nullptr, UHA, 4096, 256, 256);
  wqa_k<<<8, 256, 0, stream>>>(c_state, a_Wq, a_bq, WQA);
  tscore_k<<<1024, 256, 0, stream>>>(UHA, WQA, a_v, T);
  seg_k<<<dim3(402, 8), 256, 0, stream>>>(T, BSC, b_enc, SEG, SCO);
  final_k<<<8, 256, 0, stream>>>(SCO, SEG, out);
}

// Round 3
// 178.161 us; speedup vs baseline: 3.2664x; 2.6465x over previous
//
#include <hip/hip_runtime.h>
#include <hip/hip_bf16.h>
#include <cstdint>
#include <cstddef>

// Shapes (fixed): B=8, LB=512, LC=128, H=256, H2=512, MIN_WS=5, N_WIN=4
// Windows: ws=5,10,15,20 ; n_seg=102,101,100,99 ; total 402
// d_out: out[8*256] | s_score[8*402] | b_score[8*512]  (floats)

typedef unsigned short ushort8 __attribute__((ext_vector_type(8)));
typedef float f32x4 __attribute__((ext_vector_type(4)));

__device__ __forceinline__ float fsigmoid(float x) { return 1.0f / (1.0f + __expf(-x)); }
__device__ __forceinline__ float ftanh(float x) {
  float e = __expf(2.0f * x);
  return 1.0f - 2.0f / (e + 1.0f);
}
__device__ __forceinline__ unsigned short f2bf(float x) {
  union { float f; unsigned u; } v; v.f = x;
  unsigned r = (v.u + 0x7FFFu + ((v.u >> 16) & 1u)) >> 16;
  return (unsigned short)r;
}
__device__ __forceinline__ f32x4 mfma_bf16(ushort8 a, ushort8 b, f32x4 c) {
  asm("v_mfma_f32_16x16x32_bf16 %0, %1, %2, %0" : "+v"(c) : "v"(a), "v"(b));
  return c;
}

// ---------------- weight transpose+convert: W[k][n] f32 -> WT[n][k] bf16 -------
struct WArg { const float* s[15]; };
__global__ __launch_bounds__(256) void wconv_k(WArg wa, unsigned short* __restrict__ WT) {
  const int mat = blockIdx.z;
  const int Kd = (mat == 14) ? 256 : 512;
  if (mat == 14 && (blockIdx.x >= 4 || blockIdx.y >= 4)) return;
  const float* __restrict__ S = wa.s[mat];
  unsigned short* __restrict__ D = WT + (size_t)mat * 262144;
  const int k0 = blockIdx.y * 64, n0 = blockIdx.x * 64;
  __shared__ float tile[64][65];
  const int t = threadIdx.x;
#pragma unroll
  for (int i = 0; i < 16; ++i) {
    int id = i * 256 + t, r = id >> 6, c = id & 63;
    tile[r][c] = S[(size_t)(k0 + r) * Kd + (n0 + c)];
  }
  __syncthreads();
#pragma unroll
  for (int i = 0; i < 16; ++i) {
    int id = i * 256 + t, r = id >> 6, c = id & 63;
    D[(size_t)(n0 + r) * Kd + (k0 + c)] = f2bf(tile[c][r]);
  }
}

// ---------------- concat: [enc | broadcast c_state] -> X0 bf16 (M x 512) -------
__global__ __launch_bounds__(256) void concat_k(const float* __restrict__ enc,
                                                const float* __restrict__ cs,
                                                unsigned short* __restrict__ out, int Lshift) {
  int i4 = blockIdx.x * 256 + threadIdx.x;   // over M*128 float4-chunks
  int row = i4 >> 7, c4 = (i4 & 127) << 2;
  float4 v;
  if (c4 < 256) v = *(const float4*)(enc + ((size_t)row << 8) + c4);
  else          v = *(const float4*)(cs + ((size_t)(row >> Lshift) << 8) + (c4 - 256));
  union { unsigned short u[4]; uint2 w; } o;
  o.u[0] = f2bf(v.x); o.u[1] = f2bf(v.y); o.u[2] = f2bf(v.z); o.u[3] = f2bf(v.w);
  *(uint2*)(out + ((size_t)row << 9) + c4) = o.w;
}

// ---------------- MFMA GEMM: Y = epi(A[M][lda](bf16) @ WT[N][K]^T + bias) ------
// EPI=0: f32 out (+bias if B0)   EPI=1: highway bf16 out (NB=3)
// EPI=2: f32 exp(2*(x+bias))     EPI=3: f32 exp(2*x), transposed [b][col][row&127]
template <int NB, int EPI>
__global__ __launch_bounds__(256) void mgemm_k(
    const unsigned short* __restrict__ A, int lda,
    const unsigned short* __restrict__ W0, const unsigned short* __restrict__ W1,
    const unsigned short* __restrict__ W2,
    const float* __restrict__ B0, const float* __restrict__ B1, const float* __restrict__ B2,
    void* __restrict__ Yv, int M, int N, int K) {
  __shared__ unsigned short sm[(1 + NB) * 4096];   // A tile + NB B tiles, 64x64 bf16 each
  const int t = threadIdx.x;
  const int m0 = blockIdx.y * 64, n0 = blockIdx.x * 64;
  const int lane = t & 63, wid = t >> 6;
  const int wr = wid >> 1, wc = wid & 1;

  // staging: thread t loads 16B chunks (t) and (t+256) of each 8KB tile.
  // LDS dest linear; source chunk pre-swizzled so READS at chunk^(row&7) see linear k.
  const int srow = t >> 3;
  const int cg = (t & 7) ^ (srow & 7);
  const unsigned short* Ag0 = A + (size_t)(m0 + srow) * lda + cg * 8;
  const unsigned short* Ag1 = A + (size_t)(m0 + 32 + srow) * lda + cg * 8;
  const unsigned short* Wp[3] = {W0, W1, W2};
  const unsigned short* Bg0[NB], * Bg1[NB];
#pragma unroll
  for (int p = 0; p < NB; ++p) {
    Bg0[p] = Wp[p] + (size_t)(n0 + srow) * K + cg * 8;
    Bg1[p] = Wp[p] + (size_t)(n0 + 32 + srow) * K + cg * 8;
  }
  const int d0 = t * 8, d1 = (256 + t) * 8;   // ushort offsets in tile

  // fragment LDS offsets (k0-independent): row stride 64 ushorts, swizzled chunk
  const int fl = lane & 15, lg = lane >> 4;
  int offA[2][2], offB[2][2];
#pragma unroll
  for (int f = 0; f < 2; ++f) {
    int ra = wr * 32 + f * 16 + fl;
    int rb = wc * 32 + f * 16 + fl;
#pragma unroll
    for (int ks = 0; ks < 2; ++ks) {
      offA[f][ks] = ra * 64 + ((((ks << 2) + lg) ^ (ra & 7)) << 3);
      offB[f][ks] = rb * 64 + ((((ks << 2) + lg) ^ (rb & 7)) << 3);
    }
  }

  f32x4 acc[NB][2][2];
#pragma unroll
  for (int p = 0; p < NB; ++p)
#pragma unroll
    for (int i = 0; i < 2; ++i)
#pragma unroll
      for (int j = 0; j < 2; ++j) acc[p][i][j] = (f32x4){0.f, 0.f, 0.f, 0.f};

  // prefetch tile 0
  ushort8 ra0 = *(const ushort8*)Ag0, ra1 = *(const ushort8*)Ag1;
  ushort8 rb0[NB], rb1[NB];
#pragma unroll
  for (int p = 0; p < NB; ++p) { rb0[p] = *(const ushort8*)Bg0[p]; rb1[p] = *(const ushort8*)Bg1[p]; }

  for (int k0 = 0; k0 < K; k0 += 64) {
    __syncthreads();
    *(ushort8*)&sm[d0] = ra0;
    *(ushort8*)&sm[d1] = ra1;
#pragma unroll
    for (int p = 0; p < NB; ++p) {
      unsigned short* Bs = (unsigned short*)sm + (1 + p) * 4096;
      *(ushort8*)&Bs[d0] = rb0[p];
      *(ushort8*)&Bs[d1] = rb1[p];
    }
    __syncthreads();
    if (k0 + 64 < K) {
      ra0 = *(const ushort8*)(Ag0 + k0 + 64);
      ra1 = *(const ushort8*)(Ag1 + k0 + 64);
#pragma unroll
      for (int p = 0; p < NB; ++p) {
        rb0[p] = *(const ushort8*)(Bg0[p] + k0 + 64);
        rb1[p] = *(const ushort8*)(Bg1[p] + k0 + 64);
      }
    }
#pragma unroll
    for (int ks = 0; ks < 2; ++ks) {
      ushort8 a0 = *(const ushort8*)&sm[offA[0][ks]];
      ushort8 a1 = *(const ushort8*)&sm[offA[1][ks]];
#pragma unroll
      for (int p = 0; p < NB; ++p) {
        const unsigned short* Bs = (const unsigned short*)sm + (1 + p) * 4096;
        ushort8 b0 = *(const ushort8*)&Bs[offB[0][ks]];
        ushort8 b1 = *(const ushort8*)&Bs[offB[1][ks]];
        acc[p][0][0] = mfma_bf16(a0, b0, acc[p][0][0]);
        acc[p][0][1] = mfma_bf16(a0, b1, acc[p][0][1]);
        acc[p][1][0] = mfma_bf16(a1, b0, acc[p][1][0]);
        acc[p][1][1] = mfma_bf16(a1, b1, acc[p][1][1]);
      }
    }
  }
  asm volatile("s_nop 7\n\ts_nop 7" ::);   // MFMA -> VALU read hazard guard

#pragma unroll
  for (int mf = 0; mf < 2; ++mf) {
#pragma unroll
    for (int nf = 0; nf < 2; ++nf) {
      const int col = n0 + wc * 32 + nf * 16 + fl;
      const int row0 = m0 + wr * 32 + mf * 16 + lg * 4;
      if constexpr (EPI == 1) {
        float bn = B0[col], bl = B1[col], bg = B2[col];
        unsigned short* Y = (unsigned short*)Yv;
#pragma unroll
        for (int e = 0; e < 4; ++e) {
          float nv = acc[0][mf][nf][e] + bn;
          float lv = acc[1][mf][nf][e] + bl;
          float gv = fsigmoid(acc[2][mf][nf][e] + bg);
          Y[(size_t)(row0 + e) * N + col] = f2bf(gv * fmaxf(nv, 0.f) + (1.f - gv) * lv);
        }
      } else if constexpr (EPI == 2) {
        float bb = B0[col];
        float* Y = (float*)Yv;
#pragma unroll
        for (int e = 0; e < 4; ++e)
          Y[(size_t)(row0 + e) * N + col] = __expf(2.0f * (acc[0][mf][nf][e] + bb));
      } else if constexpr (EPI == 3) {
        float* Y = (float*)Yv;
        f32x4 w;
#pragma unroll
        for (int e = 0; e < 4; ++e) w[e] = __expf(2.0f * acc[0][mf][nf][e]);
        *(f32x4*)(Y + (((size_t)(row0 >> 7)) << 16) + ((size_t)col << 7) + (row0 & 127)) = w;
      } else {
        float bb = B0 ? B0[col] : 0.f;
        float* Y = (float*)Yv;
#pragma unroll
        for (int e = 0; e < 4; ++e)
          Y[(size_t)(row0 + e) * N + col] = acc[0][mf][nf][e] + bb;
      }
    }
  }
}

// -------- m-score via tanh factorization ---------------------------------------
// tanh(a+b) = 1 - 2/(1 + e^{2a} e^{2b});  b_score[row] = V - 2*min_j sum_h v/(1+Ew*Eu)
__global__ __launch_bounds__(256) void mscore_k(const float* __restrict__ EW,
                                                const float* __restrict__ UHT,
                                                const float* __restrict__ mv,   // 512
                                                float* __restrict__ bscore) {   // 4096
  __shared__ float eus[64 * 128];
  const int tid = threadIdx.x, lane = tid & 63, wid = tid >> 6;
  const int row = __builtin_amdgcn_readfirstlane(blockIdx.x * 4 + wid);
  const int b = row >> 9;
  const float* ew = EW + ((size_t)row << 9);
  const float* eub = UHT + ((size_t)b << 16);

  float V = 0.f;
#pragma unroll
  for (int k = 0; k < 8; ++k) V += mv[lane + (k << 6)];
#pragma unroll
  for (int off = 32; off; off >>= 1) V += __shfl_xor(V, off);

  float t0 = 0.f, t1 = 0.f;
  for (int c = 0; c < 8; ++c) {
    __syncthreads();
#pragma unroll
    for (int it = 0; it < 8; ++it) {
      int f4 = it * 256 + tid;
      *(float4*)&eus[f4 << 2] = *(const float4*)(eub + ((size_t)c << 13) + (f4 << 2));
    }
    __syncthreads();
#pragma unroll 8
    for (int h = 0; h < 64; ++h) {
      float e = ew[(c << 6) + h];
      float vv = mv[(c << 6) + h];
      float u0 = eus[(h << 7) + lane];
      float u1 = eus[(h << 7) + lane + 64];
      t0 += vv * __builtin_amdgcn_rcpf(__builtin_fmaf(e, u0, 1.f));
      t1 += vv * __builtin_amdgcn_rcpf(__builtin_fmaf(e, u1, 1.f));
    }
  }
  float t = fminf(t0, t1);
#pragma unroll
  for (int off = 32; off; off >>= 1) t = fminf(t, __shfl_xor(t, off));
  if (lane == 0) bscore[row] = V - 2.f * t;
}

// -------- wq_a[b,h] = sum_k c_state[b,k]*a_Wq[k,h] + a_bq[h] -------------------
__global__ __launch_bounds__(256) void wqa_k(const float* __restrict__ cs,
                                             const float* __restrict__ Wq,
                                             const float* __restrict__ bq,
                                             float* __restrict__ wqa) {
  int b = blockIdx.x, h = threadIdx.x;
  float acc = bq[h];
  for (int k = 0; k < 256; ++k) acc += cs[b * 256 + k] * Wq[k * 256 + h];
  wqa[b * 256 + h] = acc;
}

// -------- t[pos] = sum_h tanh(wqa[b,h]+uha[pos,h])*a_v[h] ----------------------
__global__ __launch_bounds__(256) void tscore_k(const float* __restrict__ uha,
                                                const float* __restrict__ wqa,
                                                const float* __restrict__ av,
                                                float* __restrict__ t) {
  const int tid = threadIdx.x, lane = tid & 63, wid = tid >> 6;
  const int pos = blockIdx.x * 4 + wid;
  const int b = pos >> 9;
  const int h0 = lane << 2;
  float4 u = *(const float4*)(uha + (size_t)pos * 256 + h0);
  float4 w = *(const float4*)(wqa + b * 256 + h0);
  float4 v = *(const float4*)(av + h0);
  float s = ftanh(w.x + u.x) * v.x + ftanh(w.y + u.y) * v.y +
            ftanh(w.z + u.z) * v.z + ftanh(w.w + u.w) * v.w;
#pragma unroll
  for (int off = 32; off; off >>= 1) s += __shfl_xor(s, off);
  if (lane == 0) t[pos] = s;
}

// -------- per-segment softmax over window of t, weighted sum of b_enc rows -----
__global__ __launch_bounds__(256) void seg_k(const float* __restrict__ t,
                                             const float* __restrict__ bscore,
                                             const float* __restrict__ benc,
                                             float* __restrict__ seg,
                                             float* __restrict__ sco) {
  const int s = blockIdx.x, b = blockIdx.y, h = threadIdx.x;
  int i, n;
  if (s < 102)      { i = 0; n = s; }
  else if (s < 203) { i = 1; n = s - 102; }
  else if (s < 303) { i = 2; n = s - 203; }
  else              { i = 3; n = s - 303; }
  const int ws = 5 * (i + 1), start = n * 5;
  const float* tb = t + b * 512 + start;
  float mx = -3.0e38f;
  for (int w = 0; w < ws; ++w) mx = fmaxf(mx, tb[w]);
  float sum = 0.f;
  for (int w = 0; w < ws; ++w) sum += __expf(tb[w] - mx);
  float inv = 1.f / sum;
  float acc = 0.f;
  for (int w = 0; w < ws; ++w)
    acc += __expf(tb[w] - mx) * benc[((size_t)(b * 512 + start + w)) * 256 + h];
  seg[((size_t)(b * 402 + s)) * 256 + h] = acc * inv;
  if (h == 0) {
    float ss = 0.f;
    const float* bs = bscore + b * 512 + start;
    for (int w = 0; w < ws; ++w) ss += bs[w];
    sco[b * 402 + s] = ss;
  }
}

// -------- final: s_score = softmax(scores); out = s_score @ segments -----------
__global__ __launch_bounds__(256) void final_k(const float* __restrict__ sco,
                                               const float* __restrict__ seg,
                                               float* __restrict__ dout) {
  const int b = blockIdx.x, tid = threadIdx.x, lane = tid & 63, wid = tid >> 6;
  __shared__ float sc[402];
  __shared__ float redm[4], reds[4];
  for (int s = tid; s < 402; s += 256) sc[s] = sco[b * 402 + s];
  __syncthreads();
  float m = -3.0e38f;
  for (int s = tid; s < 402; s += 256) m = fmaxf(m, sc[s]);
#pragma unroll
  for (int off = 32; off; off >>= 1) m = fmaxf(m, __shfl_xor(m, off));
  if (lane == 0) redm[wid] = m;
  __syncthreads();
  m = fmaxf(fmaxf(redm[0], redm[1]), fmaxf(redm[2], redm[3]));
  float p = 0.f;
  for (int s = tid; s < 402; s += 256) p += __expf(sc[s] - m);
#pragma unroll
  for (int off = 32; off; off >>= 1) p += __shfl_xor(p, off);
  if (lane == 0) reds[wid] = p;
  __syncthreads();
  float invS = 1.f / (reds[0] + reds[1] + reds[2] + reds[3]);
  for (int s = tid; s < 402; s += 256) {
    float pv = __expf(sc[s] - m) * invS;
    dout[2048 + b * 402 + s] = pv;
    sc[s] = pv;
  }
  __syncthreads();
  float acc = 0.f;
  for (int s = 0; s < 402; ++s)
    acc += sc[s] * seg[((size_t)(b * 402 + s)) * 256 + tid];
  dout[b * 256 + tid] = acc;
}

extern "C" void kernel_launch(void* const* d_in, const int* in_sizes, int n_in,
                              void* d_out, int out_size, void* d_ws, size_t ws_size,
                              hipStream_t stream) {
  const float* b_enc   = (const float*)d_in[0];
  const float* c_enc   = (const float*)d_in[1];
  const float* c_state = (const float*)d_in[2];
  const float* bh_Wn = (const float*)d_in[5];
  const float* bh_bn = (const float*)d_in[6];
  const float* bh_Wl = (const float*)d_in[7];
  const float* bh_bl = (const float*)d_in[8];
  const float* bh_Wg = (const float*)d_in[9];
  const float* bh_bg = (const float*)d_in[10];
  const float* ch_Wn = (const float*)d_in[11];
  const float* ch_bn = (const float*)d_in[12];
  const float* ch_Wl = (const float*)d_in[13];
  const float* ch_bl = (const float*)d_in[14];
  const float* ch_Wg = (const float*)d_in[15];
  const float* ch_bg = (const float*)d_in[16];
  const float* m_Wq  = (const float*)d_in[17];
  const float* m_bq  = (const float*)d_in[18];
  const float* m_Wk  = (const float*)d_in[19];
  const float* m_v   = (const float*)d_in[20];
  const float* a_Wq  = (const float*)d_in[21];
  const float* a_bq  = (const float*)d_in[22];
  const float* a_Wk  = (const float*)d_in[23];
  const float* a_v   = (const float*)d_in[24];

  uint8_t* base = (uint8_t*)d_ws;
  unsigned short* WT  = (unsigned short*)(base);            // 14 x 512x512 bf16
  unsigned short* WTa = WT + 14 * 262144;                   // 256x256 bf16
  unsigned short* XB0 = (unsigned short*)(base + 7471104);  // 4096x512 bf16
  unsigned short* XB1 = (unsigned short*)(base + 11665408); // 4096x512 bf16
  unsigned short* XC0 = (unsigned short*)(base + 15859712); // 1024x512 bf16
  unsigned short* XC1 = (unsigned short*)(base + 16908288); // 1024x512 bf16
  float* EW   = (float*)(base + 17956864);                  // 4096x512 f32
  float* UHT  = (float*)(base + 26345472);                  // 8x512x128 f32
  float* UHA  = (float*)(base + 28442624);                  // 4096x256 f32
  float* WQA  = (float*)(base + 32636928);
  float* T    = (float*)(base + 32645120);
  float* SEG  = (float*)(base + 32661504);                  // 8x402x256 f32
  float* SCO  = (float*)(base + 35954688);

  float* out = (float*)d_out;
  float* BSC = out + 5264;

  const int S = 262144;   // 512*512 (ushort elements per transposed weight)
  const int LW = 262144;  // f32 elements per layer in stacked weights

  WArg wa;
  wa.s[0] = bh_Wn; wa.s[1] = bh_Wn + LW;
  wa.s[2] = bh_Wl; wa.s[3] = bh_Wl + LW;
  wa.s[4] = bh_Wg; wa.s[5] = bh_Wg + LW;
  wa.s[6] = ch_Wn; wa.s[7] = ch_Wn + LW;
  wa.s[8] = ch_Wl; wa.s[9] = ch_Wl + LW;
  wa.s[10] = ch_Wg; wa.s[11] = ch_Wg + LW;
  wa.s[12] = m_Wq; wa.s[13] = m_Wk; wa.s[14] = a_Wk;

  wconv_k<<<dim3(8, 8, 15), 256, 0, stream>>>(wa, WT);
  concat_k<<<2048, 256, 0, stream>>>(b_enc, c_state, XB0, 9);
  concat_k<<<512, 256, 0, stream>>>(c_enc, c_state, XC0, 7);

  // window path uh_a: A = b_enc half of XB0 (lda=512, K=256)
  mgemm_k<1, 0><<<dim3(4, 64), 256, 0, stream>>>(XB0, 512, WTa, nullptr, nullptr,
      nullptr, nullptr, nullptr, UHA, 4096, 256, 256);

  // highway b (2 layers), c (2 layers) — fused 3-matmul + gate epilogue
  mgemm_k<3, 1><<<dim3(8, 64), 256, 0, stream>>>(XB0, 512, WT, WT + 2 * S, WT + 4 * S,
      bh_bn, bh_bl, bh_bg, XB1, 4096, 512, 512);
  mgemm_k<3, 1><<<dim3(8, 64), 256, 0, stream>>>(XB1, 512, WT + S, WT + 3 * S, WT + 5 * S,
      bh_bn + 512, bh_bl + 512, bh_bg + 512, XB0, 4096, 512, 512);
  mgemm_k<3, 1><<<dim3(8, 16), 256, 0, stream>>>(XC0, 512, WT + 6 * S, WT + 8 * S, WT + 10 * S,
      ch_bn, ch_bl, ch_bg, XC1, 1024, 512, 512);
  mgemm_k<3, 1><<<dim3(8, 16), 256, 0, stream>>>(XC1, 512, WT + 7 * S, WT + 9 * S, WT + 11 * S,
      ch_bn + 512, ch_bl + 512, ch_bg + 512, XC0, 1024, 512, 512);

  // m path: EW = exp(2*(b@m_Wq+bq)); UHT = exp(2*(c@m_Wk)) transposed; reduce
  mgemm_k<1, 2><<<dim3(8, 64), 256, 0, stream>>>(XB0, 512, WT + 12 * S, nullptr, nullptr,
      m_bq, nullptr, nullptr, EW, 4096, 512, 512);
  mgemm_k<1, 3><<<dim3(8, 16), 256, 0, stream>>>(XC0, 512, WT + 13 * S, nullptr, nullptr,
      nullptr, nullptr, nullptr, UHT, 1024, 512, 512);
  mscore_k<<<1024, 256, 0, stream>>>(EW, UHT, m_v, BSC);

  // window path scalars + segments + final
  wqa_k<<<8, 256, 0, stream>>>(c_state, a_Wq, a_bq, WQA);
  tscore_k<<<1024, 256, 0, stream>>>(UHA, WQA, a_v, T);
  seg_k<<<dim3(402, 8), 256, 0, stream>>>(T, BSC, b_enc, SEG, SCO);
  final_k<<<8, 256, 0, stream>>>(SCO, SEG, out);
}

// Round 4
// 164.314 us; speedup vs baseline: 3.5417x; 1.0843x over previous
//
#include <hip/hip_runtime.h>
#include <hip/hip_bf16.h>
#include <cstdint>
#include <cstddef>

// Shapes (fixed): B=8, LB=512, LC=128, H=256, H2=512, MIN_WS=5, N_WIN=4
// Windows: ws=5,10,15,20 ; n_seg=102,101,100,99 ; total 402
// d_out: out[8*256] | s_score[8*402] | b_score[8*512]  (floats)

typedef unsigned short ushort8 __attribute__((ext_vector_type(8)));
typedef float f32x4 __attribute__((ext_vector_type(4)));

__device__ __forceinline__ float fsigmoid(float x) { return 1.0f / (1.0f + __expf(-x)); }
__device__ __forceinline__ float ftanh(float x) {
  float e = __expf(2.0f * x);
  return 1.0f - 2.0f / (e + 1.0f);
}
__device__ __forceinline__ unsigned short f2bf(float x) {
  union { float f; unsigned u; } v; v.f = x;
  unsigned r = (v.u + 0x7FFFu + ((v.u >> 16) & 1u)) >> 16;
  return (unsigned short)r;
}
__device__ __forceinline__ f32x4 mfma_bf16(ushort8 a, ushort8 b, f32x4 c) {
  asm("v_mfma_f32_16x16x32_bf16 %0, %1, %2, %0" : "+v"(c) : "v"(a), "v"(b));
  return c;
}

// ---------------- prep: weight transpose/convert + concats + wqa ---------------
// blocks 0..959: wconv (15 mats x 64 tiles)
// blocks 960..3007: concat b (2048) ; 3008..3519: concat c (512) ; 3520..3527: wqa
struct WArg { const float* s[15]; };
__global__ __launch_bounds__(256) void prep_k(WArg wa, unsigned short* __restrict__ WT,
    const float* __restrict__ benc, const float* __restrict__ cenc,
    const float* __restrict__ cs,
    unsigned short* __restrict__ XB0, unsigned short* __restrict__ XC0,
    const float* __restrict__ aWq, const float* __restrict__ abq,
    float* __restrict__ wqa) {
  __shared__ float tile[64][65];
  const int blk = blockIdx.x, t = threadIdx.x;
  if (blk < 960) {
    const int mat = blk >> 6, q = blk & 63;
    const int Kd = (mat == 14) ? 256 : 512;
    const int k0 = (q >> 3) << 6, n0 = (q & 7) << 6;
    if (mat == 14 && (k0 >= 256 || n0 >= 256)) return;
    const float* __restrict__ S = wa.s[mat];
    unsigned short* __restrict__ D = WT + (size_t)mat * 262144;
#pragma unroll
    for (int i = 0; i < 16; ++i) {
      int id = i * 256 + t, r = id >> 6, c = id & 63;
      tile[r][c] = S[(size_t)(k0 + r) * Kd + (n0 + c)];
    }
    __syncthreads();
#pragma unroll
    for (int i = 0; i < 16; ++i) {
      int id = i * 256 + t, r = id >> 6, c = id & 63;
      D[(size_t)(n0 + r) * Kd + (k0 + c)] = f2bf(tile[c][r]);
    }
  } else if (blk < 3520) {
    const bool isB = blk < 3008;
    const float* enc = isB ? benc : cenc;
    unsigned short* out = isB ? XB0 : XC0;
    const int Lshift = isB ? 9 : 7;
    int i4 = (blk - (isB ? 960 : 3008)) * 256 + t;
    int row = i4 >> 7, c4 = (i4 & 127) << 2;
    float4 v;
    if (c4 < 256) v = *(const float4*)(enc + ((size_t)row << 8) + c4);
    else          v = *(const float4*)(cs + ((size_t)(row >> Lshift) << 8) + (c4 - 256));
    union { unsigned short u[4]; uint2 w; } o;
    o.u[0] = f2bf(v.x); o.u[1] = f2bf(v.y); o.u[2] = f2bf(v.z); o.u[3] = f2bf(v.w);
    *(uint2*)(out + ((size_t)row << 9) + c4) = o.w;
  } else {
    int b = blk - 3520, h = t;
    float acc = abq[h];
    for (int k = 0; k < 256; ++k) acc += cs[b * 256 + k] * aWq[k * 256 + h];
    wqa[b * 256 + h] = acc;
  }
}

// ---------------- MFMA GEMM: Y = epi(A[M][lda](bf16) @ WT[N][K]^T + bias) ------
// EPI=0: f32 out (+bias if B0)   EPI=1: highway bf16 out (NB=3)
// EPI=2: f32 exp(2*(x+bias))     EPI=3: f32 exp(2*x), transposed [b][col][row&127]
template <int NB, int EPI>
__global__ __launch_bounds__(256) void mgemm_k(
    const unsigned short* __restrict__ A, int lda,
    const unsigned short* __restrict__ W0, const unsigned short* __restrict__ W1,
    const unsigned short* __restrict__ W2,
    const float* __restrict__ B0, const float* __restrict__ B1, const float* __restrict__ B2,
    void* __restrict__ Yv, int M, int N, int K) {
  __shared__ unsigned short sm[(1 + NB) * 4096];   // A tile + NB B tiles, 64x64 bf16 each
  const int t = threadIdx.x;
  const int m0 = blockIdx.y * 64, n0 = blockIdx.x * 64;
  const int lane = t & 63, wid = t >> 6;
  const int wr = wid >> 1, wc = wid & 1;

  const int srow = t >> 3;
  const int cg = (t & 7) ^ (srow & 7);
  const unsigned short* Ag0 = A + (size_t)(m0 + srow) * lda + cg * 8;
  const unsigned short* Ag1 = A + (size_t)(m0 + 32 + srow) * lda + cg * 8;
  const unsigned short* Wp[3] = {W0, W1, W2};
  const unsigned short* Bg0[NB], * Bg1[NB];
#pragma unroll
  for (int p = 0; p < NB; ++p) {
    Bg0[p] = Wp[p] + (size_t)(n0 + srow) * K + cg * 8;
    Bg1[p] = Wp[p] + (size_t)(n0 + 32 + srow) * K + cg * 8;
  }
  const int d0 = t * 8, d1 = (256 + t) * 8;

  const int fl = lane & 15, lg = lane >> 4;
  int offA[2][2], offB[2][2];
#pragma unroll
  for (int f = 0; f < 2; ++f) {
    int ra = wr * 32 + f * 16 + fl;
    int rb = wc * 32 + f * 16 + fl;
#pragma unroll
    for (int ks = 0; ks < 2; ++ks) {
      offA[f][ks] = ra * 64 + ((((ks << 2) + lg) ^ (ra & 7)) << 3);
      offB[f][ks] = rb * 64 + ((((ks << 2) + lg) ^ (rb & 7)) << 3);
    }
  }

  f32x4 acc[NB][2][2];
#pragma unroll
  for (int p = 0; p < NB; ++p)
#pragma unroll
    for (int i = 0; i < 2; ++i)
#pragma unroll
      for (int j = 0; j < 2; ++j) acc[p][i][j] = (f32x4){0.f, 0.f, 0.f, 0.f};

  ushort8 ra0 = *(const ushort8*)Ag0, ra1 = *(const ushort8*)Ag1;
  ushort8 rb0[NB], rb1[NB];
#pragma unroll
  for (int p = 0; p < NB; ++p) { rb0[p] = *(const ushort8*)Bg0[p]; rb1[p] = *(const ushort8*)Bg1[p]; }

  for (int k0 = 0; k0 < K; k0 += 64) {
    __syncthreads();
    *(ushort8*)&sm[d0] = ra0;
    *(ushort8*)&sm[d1] = ra1;
#pragma unroll
    for (int p = 0; p < NB; ++p) {
      unsigned short* Bs = (unsigned short*)sm + (1 + p) * 4096;
      *(ushort8*)&Bs[d0] = rb0[p];
      *(ushort8*)&Bs[d1] = rb1[p];
    }
    __syncthreads();
    if (k0 + 64 < K) {
      ra0 = *(const ushort8*)(Ag0 + k0 + 64);
      ra1 = *(const ushort8*)(Ag1 + k0 + 64);
#pragma unroll
      for (int p = 0; p < NB; ++p) {
        rb0[p] = *(const ushort8*)(Bg0[p] + k0 + 64);
        rb1[p] = *(const ushort8*)(Bg1[p] + k0 + 64);
      }
    }
#pragma unroll
    for (int ks = 0; ks < 2; ++ks) {
      ushort8 a0 = *(const ushort8*)&sm[offA[0][ks]];
      ushort8 a1 = *(const ushort8*)&sm[offA[1][ks]];
#pragma unroll
      for (int p = 0; p < NB; ++p) {
        const unsigned short* Bs = (const unsigned short*)sm + (1 + p) * 4096;
        ushort8 b0 = *(const ushort8*)&Bs[offB[0][ks]];
        ushort8 b1 = *(const ushort8*)&Bs[offB[1][ks]];
        acc[p][0][0] = mfma_bf16(a0, b0, acc[p][0][0]);
        acc[p][0][1] = mfma_bf16(a0, b1, acc[p][0][1]);
        acc[p][1][0] = mfma_bf16(a1, b0, acc[p][1][0]);
        acc[p][1][1] = mfma_bf16(a1, b1, acc[p][1][1]);
      }
    }
  }
  asm volatile("s_nop 7\n\ts_nop 7" ::);   // MFMA -> VALU read hazard guard

#pragma unroll
  for (int mf = 0; mf < 2; ++mf) {
#pragma unroll
    for (int nf = 0; nf < 2; ++nf) {
      const int col = n0 + wc * 32 + nf * 16 + fl;
      const int row0 = m0 + wr * 32 + mf * 16 + lg * 4;
      if constexpr (EPI == 1) {
        float bn = B0[col], bl = B1[col], bg = B2[col];
        unsigned short* Y = (unsigned short*)Yv;
#pragma unroll
        for (int e = 0; e < 4; ++e) {
          float nv = acc[0][mf][nf][e] + bn;
          float lv = acc[1][mf][nf][e] + bl;
          float gv = fsigmoid(acc[2][mf][nf][e] + bg);
          Y[(size_t)(row0 + e) * N + col] = f2bf(gv * fmaxf(nv, 0.f) + (1.f - gv) * lv);
        }
      } else if constexpr (EPI == 2) {
        float bb = B0[col];
        float* Y = (float*)Yv;
#pragma unroll
        for (int e = 0; e < 4; ++e)
          Y[(size_t)(row0 + e) * N + col] = __expf(2.0f * (acc[0][mf][nf][e] + bb));
      } else if constexpr (EPI == 3) {
        float* Y = (float*)Yv;
        f32x4 w;
#pragma unroll
        for (int e = 0; e < 4; ++e) w[e] = __expf(2.0f * acc[0][mf][nf][e]);
        *(f32x4*)(Y + (((size_t)(row0 >> 7)) << 16) + ((size_t)col << 7) + (row0 & 127)) = w;
      } else {
        float bb = B0 ? B0[col] : 0.f;
        float* Y = (float*)Yv;
#pragma unroll
        for (int e = 0; e < 4; ++e)
          Y[(size_t)(row0 + e) * N + col] = acc[0][mf][nf][e] + bb;
      }
    }
  }
}

// -------- m-score via tanh factorization ---------------------------------------
// tanh(a+b) = 1 - 2/(1 + e^{2a} e^{2b});  b_score[row] = V - 2*min_j sum_h v/(1+Ew*Eu)
// v3: 8 waves/block, 8 rows/block (same b), half-wave h-split, b128 u-reads,
//     e/v chunk-preload from LDS, double-buffered Eu staging (reg prefetch).
__global__ __launch_bounds__(512) void mscore_k(const float* __restrict__ EW,   // 4096x512
                                                const float* __restrict__ UHT,  // 8x512x128
                                                const float* __restrict__ mv,   // 512
                                                float* __restrict__ bscore) {   // 4096
  __shared__ float eu[2][32 * 128];   // 2 x 16KB chunk: [hloc][j]
  __shared__ float ews[8][512];       // 16KB: this block's 8 EW rows
  __shared__ float vvs[512];          // 2KB
  const int t = threadIdx.x, lane = t & 63, wid = t >> 6;
  const int blk = blockIdx.x;                  // 512 blocks
  const int b = blk >> 6;
  const int rg = (blk & 63) << 3;              // row group base within b
  const int row = (b << 9) + rg + wid;
  const float* __restrict__ eub = UHT + ((size_t)b << 16);

  // stage 8 EW rows (4096 f32 = 1024 float4, 2 per thread)
#pragma unroll
  for (int i = 0; i < 2; ++i) {
    int f4 = i * 512 + t, r = f4 >> 7, c = (f4 & 127) << 2;
    *(float4*)&ews[r][c] = *(const float4*)(EW + (((size_t)((b << 9) + rg + r)) << 9) + c);
  }
  if (t < 128) *(float4*)&vvs[t << 2] = *(const float4*)(mv + (t << 2));

  // V = sum_h mv[h]
  float V = 0.f;
#pragma unroll
  for (int k = 0; k < 8; ++k) V += mv[lane + (k << 6)];
#pragma unroll
  for (int off = 32; off; off >>= 1) V += __shfl_xor(V, off);

  // stage Eu chunk 0 (4096 f32 = 1024 float4, 2 per thread)
  {
    float4 a = *(const float4*)(eub + (t << 2));
    float4 c = *(const float4*)(eub + ((512 + t) << 2));
    *(float4*)&eu[0][t << 2] = a;
    *(float4*)&eu[0][(512 + t) << 2] = c;
  }

  const int jg = lane & 31, hh = lane >> 5;    // j-quad = 4*jg ; h-half = hh
  f32x4 tj = (f32x4){0.f, 0.f, 0.f, 0.f};
  float e_reg[16], v_reg[16];

  for (int c = 0; c < 16; ++c) {
    __syncthreads();                           // eu[c&1] (and ews/vvs at c==0) ready
    float4 na, nb;
    if (c < 15) {                              // prefetch next chunk to regs
      const float* src = eub + ((size_t)(c + 1) << 12);
      na = *(const float4*)(src + (t << 2));
      nb = *(const float4*)(src + ((512 + t) << 2));
    }
    const int hbase = (c << 5) + (hh << 4);
#pragma unroll
    for (int q = 0; q < 4; ++q) {
      *(float4*)&e_reg[q << 2] = *(const float4*)&ews[wid][hbase + (q << 2)];
      *(float4*)&v_reg[q << 2] = *(const float4*)&vvs[hbase + (q << 2)];
    }
    const float* eup = &eu[c & 1][(hh << 11) + (jg << 2)];
#pragma unroll
    for (int i = 0; i < 16; ++i) {
      float4 u = *(const float4*)(eup + (i << 7));
      float e = e_reg[i], vv = v_reg[i];
      tj.x += vv * __builtin_amdgcn_rcpf(__builtin_fmaf(e, u.x, 1.f));
      tj.y += vv * __builtin_amdgcn_rcpf(__builtin_fmaf(e, u.y, 1.f));
      tj.z += vv * __builtin_amdgcn_rcpf(__builtin_fmaf(e, u.z, 1.f));
      tj.w += vv * __builtin_amdgcn_rcpf(__builtin_fmaf(e, u.w, 1.f));
    }
    if (c < 15) {                              // write prefetched into other buffer
      float* dst = &eu[(c + 1) & 1][0];
      *(float4*)&dst[t << 2] = na;
      *(float4*)&dst[(512 + t) << 2] = nb;
    }
  }

  // combine h-halves (lane ^ 32 holds same j-quad, other h-half)
  tj.x += __shfl_xor(tj.x, 32);
  tj.y += __shfl_xor(tj.y, 32);
  tj.z += __shfl_xor(tj.z, 32);
  tj.w += __shfl_xor(tj.w, 32);
  float tm = fminf(fminf(tj.x, tj.y), fminf(tj.z, tj.w));
#pragma unroll
  for (int off = 16; off; off >>= 1) tm = fminf(tm, __shfl_xor(tm, off));
  if (lane == 0) bscore[row] = V - 2.f * tm;
}

// -------- t[pos] = sum_h tanh(wqa[b,h]+uha[pos,h])*a_v[h] ----------------------
__global__ __launch_bounds__(256) void tscore_k(const float* __restrict__ uha,
                                                const float* __restrict__ wqa,
                                                const float* __restrict__ av,
                                                float* __restrict__ t) {
  const int tid = threadIdx.x, lane = tid & 63, wid = tid >> 6;
  const int pos = blockIdx.x * 4 + wid;
  const int b = pos >> 9;
  const int h0 = lane << 2;
  float4 u = *(const float4*)(uha + (size_t)pos * 256 + h0);
  float4 w = *(const float4*)(wqa + b * 256 + h0);
  float4 v = *(const float4*)(av + h0);
  float s = ftanh(w.x + u.x) * v.x + ftanh(w.y + u.y) * v.y +
            ftanh(w.z + u.z) * v.z + ftanh(w.w + u.w) * v.w;
#pragma unroll
  for (int off = 32; off; off >>= 1) s += __shfl_xor(s, off);
  if (lane == 0) t[pos] = s;
}

// -------- per-segment softmax over window of t, weighted sum of b_enc rows -----
__global__ __launch_bounds__(256) void seg_k(const float* __restrict__ t,
                                             const float* __restrict__ bscore,
                                             const float* __restrict__ benc,
                                             float* __restrict__ seg,
                                             float* __restrict__ sco) {
  const int s = blockIdx.x, b = blockIdx.y, h = threadIdx.x;
  int i, n;
  if (s < 102)      { i = 0; n = s; }
  else if (s < 203) { i = 1; n = s - 102; }
  else if (s < 303) { i = 2; n = s - 203; }
  else              { i = 3; n = s - 303; }
  const int ws = 5 * (i + 1), start = n * 5;
  const float* tb = t + b * 512 + start;
  float mx = -3.0e38f;
  for (int w = 0; w < ws; ++w) mx = fmaxf(mx, tb[w]);
  float sum = 0.f;
  for (int w = 0; w < ws; ++w) sum += __expf(tb[w] - mx);
  float inv = 1.f / sum;
  float acc = 0.f;
  for (int w = 0; w < ws; ++w)
    acc += __expf(tb[w] - mx) * benc[((size_t)(b * 512 + start + w)) * 256 + h];
  seg[((size_t)(b * 402 + s)) * 256 + h] = acc * inv;
  if (h == 0) {
    float ss = 0.f;
    const float* bs = bscore + b * 512 + start;
    for (int w = 0; w < ws; ++w) ss += bs[w];
    sco[b * 402 + s] = ss;
  }
}

// -------- final: s_score = softmax(scores); out = s_score @ segments -----------
__global__ __launch_bounds__(256) void final_k(const float* __restrict__ sco,
                                               const float* __restrict__ seg,
                                               float* __restrict__ dout) {
  const int b = blockIdx.x, tid = threadIdx.x, lane = tid & 63, wid = tid >> 6;
  __shared__ float sc[402];
  __shared__ float redm[4], reds[4];
  for (int s = tid; s < 402; s += 256) sc[s] = sco[b * 402 + s];
  __syncthreads();
  float m = -3.0e38f;
  for (int s = tid; s < 402; s += 256) m = fmaxf(m, sc[s]);
#pragma unroll
  for (int off = 32; off; off >>= 1) m = fmaxf(m, __shfl_xor(m, off));
  if (lane == 0) redm[wid] = m;
  __syncthreads();
  m = fmaxf(fmaxf(redm[0], redm[1]), fmaxf(redm[2], redm[3]));
  float p = 0.f;
  for (int s = tid; s < 402; s += 256) p += __expf(sc[s] - m);
#pragma unroll
  for (int off = 32; off; off >>= 1) p += __shfl_xor(p, off);
  if (lane == 0) reds[wid] = p;
  __syncthreads();
  float invS = 1.f / (reds[0] + reds[1] + reds[2] + reds[3]);
  for (int s = tid; s < 402; s += 256) {
    float pv = __expf(sc[s] - m) * invS;
    dout[2048 + b * 402 + s] = pv;
    sc[s] = pv;
  }
  __syncthreads();
  float acc = 0.f;
  for (int s = 0; s < 402; ++s)
    acc += sc[s] * seg[((size_t)(b * 402 + s)) * 256 + tid];
  dout[b * 256 + tid] = acc;
}

extern "C" void kernel_launch(void* const* d_in, const int* in_sizes, int n_in,
                              void* d_out, int out_size, void* d_ws, size_t ws_size,
                              hipStream_t stream) {
  const float* b_enc   = (const float*)d_in[0];
  const float* c_enc   = (const float*)d_in[1];
  const float* c_state = (const float*)d_in[2];
  const float* bh_Wn = (const float*)d_in[5];
  const float* bh_bn = (const float*)d_in[6];
  const float* bh_Wl = (const float*)d_in[7];
  const float* bh_bl = (const float*)d_in[8];
  const float* bh_Wg = (const float*)d_in[9];
  const float* bh_bg = (const float*)d_in[10];
  const float* ch_Wn = (const float*)d_in[11];
  const float* ch_bn = (const float*)d_in[12];
  const float* ch_Wl = (const float*)d_in[13];
  const float* ch_bl = (const float*)d_in[14];
  const float* ch_Wg = (const float*)d_in[15];
  const float* ch_bg = (const float*)d_in[16];
  const float* m_Wq  = (const float*)d_in[17];
  const float* m_bq  = (const float*)d_in[18];
  const float* m_Wk  = (const float*)d_in[19];
  const float* m_v   = (const float*)d_in[20];
  const float* a_Wq  = (const float*)d_in[21];
  const float* a_bq  = (const float*)d_in[22];
  const float* a_Wk  = (const float*)d_in[23];
  const float* a_v   = (const float*)d_in[24];

  uint8_t* base = (uint8_t*)d_ws;
  unsigned short* WT  = (unsigned short*)(base);            // 14 x 512x512 bf16
  unsigned short* WTa = WT + 14 * 262144;                   // 256x256 bf16
  unsigned short* XB0 = (unsigned short*)(base + 7471104);  // 4096x512 bf16
  unsigned short* XB1 = (unsigned short*)(base + 11665408); // 4096x512 bf16
  unsigned short* XC0 = (unsigned short*)(base + 15859712); // 1024x512 bf16
  unsigned short* XC1 = (unsigned short*)(base + 16908288); // 1024x512 bf16
  float* EW   = (float*)(base + 17956864);                  // 4096x512 f32
  float* UHT  = (float*)(base + 26345472);                  // 8x512x128 f32
  float* UHA  = (float*)(base + 28442624);                  // 4096x256 f32
  float* WQA  = (float*)(base + 32636928);
  float* T    = (float*)(base + 32645120);
  float* SEG  = (float*)(base + 32661504);                  // 8x402x256 f32
  float* SCO  = (float*)(base + 35954688);

  float* out = (float*)d_out;
  float* BSC = out + 5264;

  const int S = 262144;
  const int LW = 262144;

  WArg wa;
  wa.s[0] = bh_Wn; wa.s[1] = bh_Wn + LW;
  wa.s[2] = bh_Wl; wa.s[3] = bh_Wl + LW;
  wa.s[4] = bh_Wg; wa.s[5] = bh_Wg + LW;
  wa.s[6] = ch_Wn; wa.s[7] = ch_Wn + LW;
  wa.s[8] = ch_Wl; wa.s[9] = ch_Wl + LW;
  wa.s[10] = ch_Wg; wa.s[11] = ch_Wg + LW;
  wa.s[12] = m_Wq; wa.s[13] = m_Wk; wa.s[14] = a_Wk;

  prep_k<<<3528, 256, 0, stream>>>(wa, WT, b_enc, c_enc, c_state, XB0, XC0,
                                   a_Wq, a_bq, WQA);

  // window path uh_a: A = b_enc half of XB0 (lda=512, K=256)
  mgemm_k<1, 0><<<dim3(4, 64), 256, 0, stream>>>(XB0, 512, WTa, nullptr, nullptr,
      nullptr, nullptr, nullptr, UHA, 4096, 256, 256);

  // highway b (2 layers), c (2 layers) — fused 3-matmul + gate epilogue
  mgemm_k<3, 1><<<dim3(8, 64), 256, 0, stream>>>(XB0, 512, WT, WT + 2 * S, WT + 4 * S,
      bh_bn, bh_bl, bh_bg, XB1, 4096, 512, 512);
  mgemm_k<3, 1><<<dim3(8, 64), 256, 0, stream>>>(XB1, 512, WT + S, WT + 3 * S, WT + 5 * S,
      bh_bn + 512, bh_bl + 512, bh_bg + 512, XB0, 4096, 512, 512);
  mgemm_k<3, 1><<<dim3(8, 16), 256, 0, stream>>>(XC0, 512, WT + 6 * S, WT + 8 * S, WT + 10 * S,
      ch_bn, ch_bl, ch_bg, XC1, 1024, 512, 512);
  mgemm_k<3, 1><<<dim3(8, 16), 256, 0, stream>>>(XC1, 512, WT + 7 * S, WT + 9 * S, WT + 11 * S,
      ch_bn + 512, ch_bl + 512, ch_bg + 512, XC0, 1024, 512, 512);

  // m path: EW = exp(2*(b@m_Wq+bq)); UHT = exp(2*(c@m_Wk)) transposed; reduce
  mgemm_k<1, 2><<<dim3(8, 64), 256, 0, stream>>>(XB0, 512, WT + 12 * S, nullptr, nullptr,
      m_bq, nullptr, nullptr, EW, 4096, 512, 512);
  mgemm_k<1, 3><<<dim3(8, 16), 256, 0, stream>>>(XC0, 512, WT + 13 * S, nullptr, nullptr,
      nullptr, nullptr, nullptr, UHT, 1024, 512, 512);
  mscore_k<<<512, 512, 0, stream>>>(EW, UHT, m_v, BSC);

  // window path scalars + segments + final
  tscore_k<<<1024, 256, 0, stream>>>(UHA, WQA, a_v, T);
  seg_k<<<dim3(402, 8), 256, 0, stream>>>(T, BSC, b_enc, SEG, SCO);
  final_k<<<8, 256, 0, stream>>>(SCO, SEG, out);
}

// Round 5
// 141.986 us; speedup vs baseline: 4.0986x; 1.1572x over previous
//
#include <hip/hip_runtime.h>
#include <hip/hip_bf16.h>
#include <cstdint>
#include <cstddef>

// Shapes (fixed): B=8, LB=512, LC=128, H=256, H2=512, MIN_WS=5, N_WIN=4
// Windows: ws=5,10,15,20 ; n_seg=102,101,100,99 ; total 402
// d_out: out[8*256] | s_score[8*402] | b_score[8*512]  (floats)

typedef unsigned short ushort8 __attribute__((ext_vector_type(8)));
typedef float f32x4 __attribute__((ext_vector_type(4)));

__device__ __forceinline__ float fsigmoid(float x) { return 1.0f / (1.0f + __expf(-x)); }
__device__ __forceinline__ float ftanh(float x) {
  float e = __expf(2.0f * x);
  return 1.0f - 2.0f / (e + 1.0f);
}
__device__ __forceinline__ unsigned short f2bf(float x) {
  union { float f; unsigned u; } v; v.f = x;
  unsigned r = (v.u + 0x7FFFu + ((v.u >> 16) & 1u)) >> 16;
  return (unsigned short)r;
}
__device__ __forceinline__ f32x4 mfma_bf16(ushort8 a, ushort8 b, f32x4 c) {
  asm("v_mfma_f32_16x16x32_bf16 %0, %1, %2, %0" : "+v"(c) : "v"(a), "v"(b));
  return c;
}

// ---------------- prep: weight transpose/convert + concats + wqa ---------------
struct WArg { const float* s[15]; };
__global__ __launch_bounds__(256) void prep_k(WArg wa, unsigned short* __restrict__ WT,
    const float* __restrict__ benc, const float* __restrict__ cenc,
    const float* __restrict__ cs,
    unsigned short* __restrict__ XB0, unsigned short* __restrict__ XC0,
    const float* __restrict__ aWq, const float* __restrict__ abq,
    float* __restrict__ wqa) {
  __shared__ float tile[64][65];
  const int blk = blockIdx.x, t = threadIdx.x;
  if (blk < 960) {
    const int mat = blk >> 6, q = blk & 63;
    const int Kd = (mat == 14) ? 256 : 512;
    const int k0 = (q >> 3) << 6, n0 = (q & 7) << 6;
    if (mat == 14 && (k0 >= 256 || n0 >= 256)) return;
    const float* __restrict__ S = wa.s[mat];
    unsigned short* __restrict__ D = WT + (size_t)mat * 262144;
#pragma unroll
    for (int i = 0; i < 16; ++i) {
      int id = i * 256 + t, r = id >> 6, c = id & 63;
      tile[r][c] = S[(size_t)(k0 + r) * Kd + (n0 + c)];
    }
    __syncthreads();
#pragma unroll
    for (int i = 0; i < 16; ++i) {
      int id = i * 256 + t, r = id >> 6, c = id & 63;
      D[(size_t)(n0 + r) * Kd + (k0 + c)] = f2bf(tile[c][r]);
    }
  } else if (blk < 3520) {
    const bool isB = blk < 3008;
    const float* enc = isB ? benc : cenc;
    unsigned short* out = isB ? XB0 : XC0;
    const int Lshift = isB ? 9 : 7;
    int i4 = (blk - (isB ? 960 : 3008)) * 256 + t;
    int row = i4 >> 7, c4 = (i4 & 127) << 2;
    float4 v;
    if (c4 < 256) v = *(const float4*)(enc + ((size_t)row << 8) + c4);
    else          v = *(const float4*)(cs + ((size_t)(row >> Lshift) << 8) + (c4 - 256));
    union { unsigned short u[4]; uint2 w; } o;
    o.u[0] = f2bf(v.x); o.u[1] = f2bf(v.y); o.u[2] = f2bf(v.z); o.u[3] = f2bf(v.w);
    *(uint2*)(out + ((size_t)row << 9) + c4) = o.w;
  } else {
    int b = blk - 3520, h = t;
    float acc = abq[h];
    for (int k = 0; k < 256; ++k) acc += cs[b * 256 + k] * aWq[k * 256 + h];
    wqa[b * 256 + h] = acc;
  }
}

// ---------------- merged MFMA GEMM launcher ------------------------------------
// epi: 0 plain f32 (+bias if B0), 1 highway bf16 (NB=3), 2 f32 exp(2*(x+b)),
//      3 f32 exp(2*x) transposed [b][col][row&127]
struct GJob {
  const unsigned short* A; const unsigned short* W0;
  const unsigned short* W1; const unsigned short* W2;
  const float* B0; const float* B1; const float* B2;
  void* Y; int lda, N, K, nbxs /*log2 blocks in x*/, epi, nb, blk0;
};

template <int NB>
__device__ __forceinline__ void gemm_body(const GJob& j, int bx, int by,
                                          unsigned short* sm, int t) {
  const int m0 = by * 64, n0 = bx * 64;
  const int lane = t & 63, wid = t >> 6;
  const int wr = wid >> 1, wc = wid & 1;
  const int N = j.N, K = j.K, lda = j.lda;

  const int srow = t >> 3;
  const int cg = (t & 7) ^ (srow & 7);
  const unsigned short* Ag0 = j.A + (size_t)(m0 + srow) * lda + cg * 8;
  const unsigned short* Ag1 = j.A + (size_t)(m0 + 32 + srow) * lda + cg * 8;
  const unsigned short* Wp[3] = {j.W0, j.W1, j.W2};
  const unsigned short* Bg0[NB], * Bg1[NB];
#pragma unroll
  for (int p = 0; p < NB; ++p) {
    Bg0[p] = Wp[p] + (size_t)(n0 + srow) * K + cg * 8;
    Bg1[p] = Wp[p] + (size_t)(n0 + 32 + srow) * K + cg * 8;
  }
  const int d0 = t * 8, d1 = (256 + t) * 8;

  const int fl = lane & 15, lg = lane >> 4;
  int offA[2][2], offB[2][2];
#pragma unroll
  for (int f = 0; f < 2; ++f) {
    int ra = wr * 32 + f * 16 + fl;
    int rb = wc * 32 + f * 16 + fl;
#pragma unroll
    for (int ks = 0; ks < 2; ++ks) {
      offA[f][ks] = ra * 64 + ((((ks << 2) + lg) ^ (ra & 7)) << 3);
      offB[f][ks] = rb * 64 + ((((ks << 2) + lg) ^ (rb & 7)) << 3);
    }
  }

  f32x4 acc[NB][2][2];
#pragma unroll
  for (int p = 0; p < NB; ++p)
#pragma unroll
    for (int i = 0; i < 2; ++i)
#pragma unroll
      for (int q = 0; q < 2; ++q) acc[p][i][q] = (f32x4){0.f, 0.f, 0.f, 0.f};

  ushort8 ra0 = *(const ushort8*)Ag0, ra1 = *(const ushort8*)Ag1;
  ushort8 rb0[NB], rb1[NB];
#pragma unroll
  for (int p = 0; p < NB; ++p) { rb0[p] = *(const ushort8*)Bg0[p]; rb1[p] = *(const ushort8*)Bg1[p]; }

  for (int k0 = 0; k0 < K; k0 += 64) {
    __syncthreads();
    *(ushort8*)&sm[d0] = ra0;
    *(ushort8*)&sm[d1] = ra1;
#pragma unroll
    for (int p = 0; p < NB; ++p) {
      unsigned short* Bs = sm + (1 + p) * 4096;
      *(ushort8*)&Bs[d0] = rb0[p];
      *(ushort8*)&Bs[d1] = rb1[p];
    }
    __syncthreads();
    if (k0 + 64 < K) {
      ra0 = *(const ushort8*)(Ag0 + k0 + 64);
      ra1 = *(const ushort8*)(Ag1 + k0 + 64);
#pragma unroll
      for (int p = 0; p < NB; ++p) {
        rb0[p] = *(const ushort8*)(Bg0[p] + k0 + 64);
        rb1[p] = *(const ushort8*)(Bg1[p] + k0 + 64);
      }
    }
#pragma unroll
    for (int ks = 0; ks < 2; ++ks) {
      ushort8 a0 = *(const ushort8*)&sm[offA[0][ks]];
      ushort8 a1 = *(const ushort8*)&sm[offA[1][ks]];
#pragma unroll
      for (int p = 0; p < NB; ++p) {
        const unsigned short* Bs = sm + (1 + p) * 4096;
        ushort8 b0 = *(const ushort8*)&Bs[offB[0][ks]];
        ushort8 b1 = *(const ushort8*)&Bs[offB[1][ks]];
        acc[p][0][0] = mfma_bf16(a0, b0, acc[p][0][0]);
        acc[p][0][1] = mfma_bf16(a0, b1, acc[p][0][1]);
        acc[p][1][0] = mfma_bf16(a1, b0, acc[p][1][0]);
        acc[p][1][1] = mfma_bf16(a1, b1, acc[p][1][1]);
      }
    }
  }
  asm volatile("s_nop 7\n\ts_nop 7" ::);   // MFMA -> VALU read hazard guard

#pragma unroll
  for (int mf = 0; mf < 2; ++mf) {
#pragma unroll
    for (int nf = 0; nf < 2; ++nf) {
      const int col = n0 + wc * 32 + nf * 16 + fl;
      const int row0 = m0 + wr * 32 + mf * 16 + lg * 4;
      if constexpr (NB == 3) {
        // epi == 1
        float bn = j.B0[col], bl = j.B1[col], bg = j.B2[col];
        unsigned short* Y = (unsigned short*)j.Y;
#pragma unroll
        for (int e = 0; e < 4; ++e) {
          float nv = acc[0][mf][nf][e] + bn;
          float lv = acc[1][mf][nf][e] + bl;
          float gv = fsigmoid(acc[2][mf][nf][e] + bg);
          Y[(size_t)(row0 + e) * N + col] = f2bf(gv * fmaxf(nv, 0.f) + (1.f - gv) * lv);
        }
      } else {
        float* Y = (float*)j.Y;
        if (j.epi == 2) {
          float bb = j.B0[col];
#pragma unroll
          for (int e = 0; e < 4; ++e)
            Y[(size_t)(row0 + e) * N + col] = __expf(2.0f * (acc[0][mf][nf][e] + bb));
        } else if (j.epi == 3) {
          f32x4 w;
#pragma unroll
          for (int e = 0; e < 4; ++e) w[e] = __expf(2.0f * acc[0][mf][nf][e]);
          *(f32x4*)(Y + (((size_t)(row0 >> 7)) << 16) + ((size_t)col << 7) + (row0 & 127)) = w;
        } else {
          float bb = j.B0 ? j.B0[col] : 0.f;
#pragma unroll
          for (int e = 0; e < 4; ++e)
            Y[(size_t)(row0 + e) * N + col] = acc[0][mf][nf][e] + bb;
        }
      }
    }
  }
}

// merged kernel: up to 3 gemm jobs + optional tscore tail blocks
__global__ __launch_bounds__(256) void mgemm3_k(GJob j0, GJob j1, GJob j2, int toff,
    const float* __restrict__ uha, const float* __restrict__ wqa,
    const float* __restrict__ av, float* __restrict__ tout) {
  __shared__ unsigned short sm[4 * 4096];
  const int blk = blockIdx.x, t = threadIdx.x;
  if (blk >= toff) {
    // tscore: t[pos] = sum_h tanh(wqa[b,h]+uha[pos,h])*av[h]
    const int lane = t & 63, wid = t >> 6;
    const int pos = (blk - toff) * 4 + wid;
    const int b = pos >> 9;
    const int h0 = lane << 2;
    float4 u = *(const float4*)(uha + (size_t)pos * 256 + h0);
    float4 w = *(const float4*)(wqa + b * 256 + h0);
    float4 v = *(const float4*)(av + h0);
    float s = ftanh(w.x + u.x) * v.x + ftanh(w.y + u.y) * v.y +
              ftanh(w.z + u.z) * v.z + ftanh(w.w + u.w) * v.w;
#pragma unroll
    for (int off = 32; off; off >>= 1) s += __shfl_xor(s, off);
    if (lane == 0) tout[pos] = s;
    return;
  }
  GJob j = j0;
  if (blk >= j1.blk0) j = j1;
  if (blk >= j2.blk0) j = j2;
  const int rel = blk - j.blk0;
  const int bx = rel & ((1 << j.nbxs) - 1), by = rel >> j.nbxs;
  if (j.nb == 3) gemm_body<3>(j, bx, by, sm, t);
  else          gemm_body<1>(j, bx, by, sm, t);
}

// -------- m-score via tanh factorization, 2 rows/wave ---------------------------
// tanh(a+b) = 1 - 2/(1 + e^{2a} e^{2b});  b_score[row] = V - 2*min_j sum_h v/(1+Ew*Eu)
__global__ __launch_bounds__(256) void mscore_k(const float* __restrict__ EW,   // 4096x512
                                                const float* __restrict__ UHT,  // 8x512x128
                                                const float* __restrict__ mv,   // 512
                                                float* __restrict__ bscore) {   // 4096
  __shared__ float eu[2][32 * 128];   // 2 x 16KB chunk: [hloc][j]
  __shared__ float ews[8][512];       // 16KB: block's 8 EW rows
  __shared__ float vvs[512];          // 2KB
  const int t = threadIdx.x, lane = t & 63, wid = t >> 6;
  const int blk = blockIdx.x;                  // 512 blocks
  const int b = blk >> 6, g = blk & 63;
  const int row0 = (b << 9) + (g << 3);        // block's 8 rows
  const float* __restrict__ eub = UHT + ((size_t)b << 16);

  // stage 8 EW rows (1024 float4, 4/thread)
#pragma unroll
  for (int q = 0; q < 4; ++q) {
    int f4 = q * 256 + t, r = f4 >> 7, c4 = (f4 & 127) << 2;
    *(float4*)&ews[r][c4] = *(const float4*)(EW + (((size_t)(row0 + r)) << 9) + c4);
  }
  if (t < 128) *(float4*)&vvs[t << 2] = *(const float4*)(mv + (t << 2));

  // V = sum_h mv[h]
  float V = 0.f;
#pragma unroll
  for (int k = 0; k < 8; ++k) V += mv[lane + (k << 6)];
#pragma unroll
  for (int off = 32; off; off >>= 1) V += __shfl_xor(V, off);

  // stage Eu chunk 0 (1024 float4, 4/thread)
#pragma unroll
  for (int q = 0; q < 4; ++q) {
    int f4 = q * 256 + t;
    *(float4*)&eu[0][f4 << 2] = *(const float4*)(eub + (f4 << 2));
  }

  const int jg = lane & 31, hh = lane >> 5;    // j-quad base 4*jg ; h-half
  const int lr = wid << 1;                     // this wave's local rows lr, lr+1
  f32x4 tj0 = (f32x4){0.f, 0.f, 0.f, 0.f};
  f32x4 tj1 = (f32x4){0.f, 0.f, 0.f, 0.f};
  float e0r[16], e1r[16], vr[16];

  for (int c = 0; c < 16; ++c) {
    __syncthreads();                           // eu[c&1] ready (ews/vvs at c==0)
    float4 pf0, pf1, pf2, pf3;
    if (c < 15) {                              // prefetch next chunk to regs
      const float* src = eub + ((size_t)(c + 1) << 12);
      pf0 = *(const float4*)(src + (t << 2));
      pf1 = *(const float4*)(src + ((256 + t) << 2));
      pf2 = *(const float4*)(src + ((512 + t) << 2));
      pf3 = *(const float4*)(src + ((768 + t) << 2));
    }
    const int hbase = (c << 5) + (hh << 4);
#pragma unroll
    for (int q = 0; q < 4; ++q) {
      *(float4*)&e0r[q << 2] = *(const float4*)&ews[lr][hbase + (q << 2)];
      *(float4*)&e1r[q << 2] = *(const float4*)&ews[lr + 1][hbase + (q << 2)];
      *(float4*)&vr[q << 2]  = *(const float4*)&vvs[hbase + (q << 2)];
    }
    const float* eup = &eu[c & 1][((hh << 4) << 7) + (jg << 2)];
#pragma unroll
    for (int i = 0; i < 16; ++i) {
      float4 u = *(const float4*)(eup + (i << 7));
      float vv = vr[i], e0 = e0r[i], e1 = e1r[i];
      tj0.x += vv * __builtin_amdgcn_rcpf(__builtin_fmaf(e0, u.x, 1.f));
      tj0.y += vv * __builtin_amdgcn_rcpf(__builtin_fmaf(e0, u.y, 1.f));
      tj0.z += vv * __builtin_amdgcn_rcpf(__builtin_fmaf(e0, u.z, 1.f));
      tj0.w += vv * __builtin_amdgcn_rcpf(__builtin_fmaf(e0, u.w, 1.f));
      tj1.x += vv * __builtin_amdgcn_rcpf(__builtin_fmaf(e1, u.x, 1.f));
      tj1.y += vv * __builtin_amdgcn_rcpf(__builtin_fmaf(e1, u.y, 1.f));
      tj1.z += vv * __builtin_amdgcn_rcpf(__builtin_fmaf(e1, u.z, 1.f));
      tj1.w += vv * __builtin_amdgcn_rcpf(__builtin_fmaf(e1, u.w, 1.f));
    }
    if (c < 15) {
      float* dst = &eu[(c + 1) & 1][0];
      *(float4*)&dst[t << 2] = pf0;
      *(float4*)&dst[(256 + t) << 2] = pf1;
      *(float4*)&dst[(512 + t) << 2] = pf2;
      *(float4*)&dst[(768 + t) << 2] = pf3;
    }
  }

  // combine h-halves (lane ^ 32 = same j-quad, other half)
  tj0.x += __shfl_xor(tj0.x, 32); tj0.y += __shfl_xor(tj0.y, 32);
  tj0.z += __shfl_xor(tj0.z, 32); tj0.w += __shfl_xor(tj0.w, 32);
  tj1.x += __shfl_xor(tj1.x, 32); tj1.y += __shfl_xor(tj1.y, 32);
  tj1.z += __shfl_xor(tj1.z, 32); tj1.w += __shfl_xor(tj1.w, 32);
  float m0 = fminf(fminf(tj0.x, tj0.y), fminf(tj0.z, tj0.w));
  float m1 = fminf(fminf(tj1.x, tj1.y), fminf(tj1.z, tj1.w));
#pragma unroll
  for (int off = 16; off; off >>= 1) {
    m0 = fminf(m0, __shfl_xor(m0, off));
    m1 = fminf(m1, __shfl_xor(m1, off));
  }
  if (lane == 0) {
    bscore[row0 + lr] = V - 2.f * m0;
    bscore[row0 + lr + 1] = V - 2.f * m1;
  }
}

// -------- per-segment softmax over window of t, weighted sum of b_enc rows -----
__global__ __launch_bounds__(256) void seg_k(const float* __restrict__ t,
                                             const float* __restrict__ bscore,
                                             const float* __restrict__ benc,
                                             float* __restrict__ seg,
                                             float* __restrict__ sco) {
  const int s = blockIdx.x, b = blockIdx.y, h = threadIdx.x;
  int i, n;
  if (s < 102)      { i = 0; n = s; }
  else if (s < 203) { i = 1; n = s - 102; }
  else if (s < 303) { i = 2; n = s - 203; }
  else              { i = 3; n = s - 303; }
  const int ws = 5 * (i + 1), start = n * 5;
  const float* tb = t + b * 512 + start;
  float mx = -3.0e38f;
  for (int w = 0; w < ws; ++w) mx = fmaxf(mx, tb[w]);
  float sum = 0.f;
  for (int w = 0; w < ws; ++w) sum += __expf(tb[w] - mx);
  float inv = 1.f / sum;
  float acc = 0.f;
  for (int w = 0; w < ws; ++w)
    acc += __expf(tb[w] - mx) * benc[((size_t)(b * 512 + start + w)) * 256 + h];
  seg[((size_t)(b * 402 + s)) * 256 + h] = acc * inv;
  if (h == 0) {
    float ss = 0.f;
    const float* bs = bscore + b * 512 + start;
    for (int w = 0; w < ws; ++w) ss += bs[w];
    sco[b * 402 + s] = ss;
  }
}

// -------- final: s_score = softmax(scores); out = s_score @ segments -----------
__global__ __launch_bounds__(256) void final_k(const float* __restrict__ sco,
                                               const float* __restrict__ seg,
                                               float* __restrict__ dout) {
  const int b = blockIdx.x, tid = threadIdx.x, lane = tid & 63, wid = tid >> 6;
  __shared__ float sc[402];
  __shared__ float redm[4], reds[4];
  for (int s = tid; s < 402; s += 256) sc[s] = sco[b * 402 + s];
  __syncthreads();
  float m = -3.0e38f;
  for (int s = tid; s < 402; s += 256) m = fmaxf(m, sc[s]);
#pragma unroll
  for (int off = 32; off; off >>= 1) m = fmaxf(m, __shfl_xor(m, off));
  if (lane == 0) redm[wid] = m;
  __syncthreads();
  m = fmaxf(fmaxf(redm[0], redm[1]), fmaxf(redm[2], redm[3]));
  float p = 0.f;
  for (int s = tid; s < 402; s += 256) p += __expf(sc[s] - m);
#pragma unroll
  for (int off = 32; off; off >>= 1) p += __shfl_xor(p, off);
  if (lane == 0) reds[wid] = p;
  __syncthreads();
  float invS = 1.f / (reds[0] + reds[1] + reds[2] + reds[3]);
  for (int s = tid; s < 402; s += 256) {
    float pv = __expf(sc[s] - m) * invS;
    dout[2048 + b * 402 + s] = pv;
    sc[s] = pv;
  }
  __syncthreads();
  float acc = 0.f;
  for (int s = 0; s < 402; ++s)
    acc += sc[s] * seg[((size_t)(b * 402 + s)) * 256 + tid];
  dout[b * 256 + tid] = acc;
}

extern "C" void kernel_launch(void* const* d_in, const int* in_sizes, int n_in,
                              void* d_out, int out_size, void* d_ws, size_t ws_size,
                              hipStream_t stream) {
  const float* b_enc   = (const float*)d_in[0];
  const float* c_enc   = (const float*)d_in[1];
  const float* c_state = (const float*)d_in[2];
  const float* bh_Wn = (const float*)d_in[5];
  const float* bh_bn = (const float*)d_in[6];
  const float* bh_Wl = (const float*)d_in[7];
  const float* bh_bl = (const float*)d_in[8];
  const float* bh_Wg = (const float*)d_in[9];
  const float* bh_bg = (const float*)d_in[10];
  const float* ch_Wn = (const float*)d_in[11];
  const float* ch_bn = (const float*)d_in[12];
  const float* ch_Wl = (const float*)d_in[13];
  const float* ch_bl = (const float*)d_in[14];
  const float* ch_Wg = (const float*)d_in[15];
  const float* ch_bg = (const float*)d_in[16];
  const float* m_Wq  = (const float*)d_in[17];
  const float* m_bq  = (const float*)d_in[18];
  const float* m_Wk  = (const float*)d_in[19];
  const float* m_v   = (const float*)d_in[20];
  const float* a_Wq  = (const float*)d_in[21];
  const float* a_bq  = (const float*)d_in[22];
  const float* a_Wk  = (const float*)d_in[23];
  const float* a_v   = (const float*)d_in[24];

  uint8_t* base = (uint8_t*)d_ws;
  unsigned short* WT  = (unsigned short*)(base);            // 14 x 512x512 bf16
  unsigned short* WTa = WT + 14 * 262144;                   // 256x256 bf16
  unsigned short* XB0 = (unsigned short*)(base + 7471104);  // 4096x512 bf16
  unsigned short* XB1 = (unsigned short*)(base + 11665408); // 4096x512 bf16
  unsigned short* XC0 = (unsigned short*)(base + 15859712); // 1024x512 bf16
  unsigned short* XC1 = (unsigned short*)(base + 16908288); // 1024x512 bf16
  float* EW   = (float*)(base + 17956864);                  // 4096x512 f32
  float* UHT  = (float*)(base + 26345472);                  // 8x512x128 f32
  float* UHA  = (float*)(base + 28442624);                  // 4096x256 f32
  float* WQA  = (float*)(base + 32636928);
  float* T    = (float*)(base + 32645120);
  float* SEG  = (float*)(base + 32661504);                  // 8x402x256 f32
  float* SCO  = (float*)(base + 35954688);

  float* out = (float*)d_out;
  float* BSC = out + 5264;

  const int S = 262144;
  const int LW = 262144;
  const int SENT = 1 << 30;

  WArg wa;
  wa.s[0] = bh_Wn; wa.s[1] = bh_Wn + LW;
  wa.s[2] = bh_Wl; wa.s[3] = bh_Wl + LW;
  wa.s[4] = bh_Wg; wa.s[5] = bh_Wg + LW;
  wa.s[6] = ch_Wn; wa.s[7] = ch_Wn + LW;
  wa.s[8] = ch_Wl; wa.s[9] = ch_Wl + LW;
  wa.s[10] = ch_Wg; wa.s[11] = ch_Wg + LW;
  wa.s[12] = m_Wq; wa.s[13] = m_Wk; wa.s[14] = a_Wk;

  prep_k<<<3528, 256, 0, stream>>>(wa, WT, b_enc, c_enc, c_state, XB0, XC0,
                                   a_Wq, a_bq, WQA);

  // G1: highway-b L1 (512 blk) + highway-c L1 (128 blk) + UHA gemm (256 blk)
  {
    GJob jb = {XB0, WT, WT + 2 * S, WT + 4 * S, bh_bn, bh_bl, bh_bg,
               XB1, 512, 512, 512, 3, 1, 3, 0};
    GJob jc = {XC0, WT + 6 * S, WT + 8 * S, WT + 10 * S, ch_bn, ch_bl, ch_bg,
               XC1, 512, 512, 512, 3, 1, 3, 512};
    GJob ja = {XB0, WTa, nullptr, nullptr, nullptr, nullptr, nullptr,
               UHA, 512, 256, 256, 2, 0, 1, 640};
    mgemm3_k<<<896, 256, 0, stream>>>(jb, jc, ja, 896, nullptr, nullptr, nullptr, nullptr);
  }
  // G2: highway-b L2 (512) + highway-c L2 (128)
  {
    GJob jb = {XB1, WT + S, WT + 3 * S, WT + 5 * S, bh_bn + 512, bh_bl + 512, bh_bg + 512,
               XB0, 512, 512, 512, 3, 1, 3, 0};
    GJob jc = {XC1, WT + 7 * S, WT + 9 * S, WT + 11 * S, ch_bn + 512, ch_bl + 512, ch_bg + 512,
               XC0, 512, 512, 512, 3, 1, 3, 512};
    GJob js = jc; js.blk0 = SENT;
    mgemm3_k<<<640, 256, 0, stream>>>(jb, jc, js, 640, nullptr, nullptr, nullptr, nullptr);
  }
  // G3: EW gemm (512) + UHT gemm (128) + tscore tail (1024)
  {
    GJob je = {XB0, WT + 12 * S, nullptr, nullptr, m_bq, nullptr, nullptr,
               EW, 512, 512, 512, 3, 2, 1, 0};
    GJob ju = {XC0, WT + 13 * S, nullptr, nullptr, nullptr, nullptr, nullptr,
               UHT, 512, 512, 512, 3, 3, 1, 512};
    GJob js = ju; js.blk0 = SENT;
    mgemm3_k<<<1664, 256, 0, stream>>>(je, ju, js, 640, UHA, WQA, a_v, T);
  }

  mscore_k<<<512, 256, 0, stream>>>(EW, UHT, m_v, BSC);
  seg_k<<<dim3(402, 8), 256, 0, stream>>>(T, BSC, b_enc, SEG, SCO);
  final_k<<<8, 256, 0, stream>>>(SCO, SEG, out);
}